// Round 10
// baseline (465.143 us; speedup 1.0000x reference)
//
#include <hip/hip_runtime.h>
#include <hip/hip_bf16.h>

#define N_NODES 50000
#define N_EDGES 600000
#define DIM     128
#define HMLP    256
#define NCLS    32
#define NGRAPH  512
#define NLAYER  3
#define BN_EPS  1e-5f
#define NBLK_SCAN ((N_NODES + 255) / 256)

typedef unsigned short ushort_t;
typedef unsigned int uint_t;
typedef __attribute__((ext_vector_type(8))) short short8v;
typedef __attribute__((ext_vector_type(4))) float f32x4;

#define MODE_BF16R 1
#define MODE_F32   2

__device__ __forceinline__ ushort_t f2b(float v) {
    __hip_bfloat16 h = __float2bfloat16(v);
    return *reinterpret_cast<ushort_t*>(&h);
}
__device__ __forceinline__ float b2f(ushort_t u) {
    __hip_bfloat16 h = *reinterpret_cast<__hip_bfloat16*>(&u);
    return __bfloat162float(h);
}
__device__ __forceinline__ float blo(uint_t h) { return b2f((ushort_t)(h & 0xffffu)); }
__device__ __forceinline__ float bhi(uint_t h) { return b2f((ushort_t)(h >> 16)); }

// ============ fused layer GEMM + BN-stats: Y = sum_p relu(A_p@W_p + b_p) ============
// 64-row tile, 256 threads / 4 waves; each wave: 16 rows x 128 cols (tot[8], acc[8]).
__global__ __launch_bounds__(256) void flgemm_kernel(
    const ushort_t* __restrict__ Xp,   // [N][128]
    const ushort_t* __restrict__ Agg,  // [N][384]
    const ushort_t* __restrict__ WT,   // [512][128]
    const float* __restrict__ biascat, // [512]
    ushort_t* __restrict__ Y,
    float* __restrict__ stats,         // [256]: sum | sumsq per channel
    int M)
{
    __shared__ ushort_t As[64 * 64];
    __shared__ ushort_t Bs[128 * 64];
    __shared__ float sh_s[128];
    __shared__ float sh_q[128];
    const int tid = threadIdx.x, lane = tid & 63, wv = tid >> 6;
    const int row0 = blockIdx.x * 64;
    const int fq = lane >> 4, fr = lane & 15;

    if (tid < 128) { sh_s[tid] = 0.f; sh_q[tid] = 0.f; }

    f32x4 tot[8] = {};

#pragma unroll
    for (int p = 0; p < 4; ++p) {
        const ushort_t* Ap = (p == 0) ? (Xp + (size_t)row0 * 128)
                                      : (Agg + (size_t)row0 * 384 + (p - 1) * 128);
        const int lda = (p == 0) ? 128 : 384;
        const ushort_t* Bp = WT + (size_t)p * 128 * 128;
        f32x4 acc[8] = {};
#pragma unroll
        for (int k0 = 0; k0 < 128; k0 += 64) {
#pragma unroll
            for (int i = 0; i < 2; ++i) {          // A: 64 rows x 8 slots = 512
                int sid = i * 256 + tid;
                int r = sid >> 3, sl = sid & 7, sw = sl ^ (r & 7);
                int rr = (row0 + r < M) ? r : (M - 1 - row0);
                __builtin_amdgcn_global_load_lds(
                    (const __attribute__((address_space(1))) unsigned int*)(Ap + (size_t)rr * lda + k0 + (sw << 3)),
                    (__attribute__((address_space(3))) unsigned int*)((char*)As + sid * 16), 16, 0, 0);
            }
#pragma unroll
            for (int i = 0; i < 4; ++i) {          // B: 128 rows x 8 slots = 1024
                int sid = i * 256 + tid;
                int r = sid >> 3, sl = sid & 7, sw = sl ^ (r & 7);
                __builtin_amdgcn_global_load_lds(
                    (const __attribute__((address_space(1))) unsigned int*)(Bp + (size_t)r * 128 + k0 + (sw << 3)),
                    (__attribute__((address_space(3))) unsigned int*)((char*)Bs + sid * 16), 16, 0, 0);
            }
            __syncthreads();
#pragma unroll
            for (int kk = 0; kk < 2; ++kk) {
                int ra = wv * 16 + fr;
                short8v a = *(const short8v*)((const char*)As + ra * 128 + (((kk * 4 + fq) ^ (ra & 7)) << 4));
                short8v b[8];
#pragma unroll
                for (int nf = 0; nf < 8; ++nf) {
                    int rb = nf * 16 + fr;
                    b[nf] = *(const short8v*)((const char*)Bs + rb * 128 + (((kk * 4 + fq) ^ (rb & 7)) << 4));
                }
#pragma unroll
                for (int nf = 0; nf < 8; ++nf)
                    acc[nf] = __builtin_amdgcn_mfma_f32_16x16x32_bf16(a, b[nf], acc[nf], 0, 0, 0);
            }
            __syncthreads();
        }
#pragma unroll
        for (int nf = 0; nf < 8; ++nf) {
            float bv = biascat[p * 128 + nf * 16 + fr];
#pragma unroll
            for (int j = 0; j < 4; ++j)
                tot[nf][j] += fmaxf(acc[nf][j] + bv, 0.f);
        }
    }
    // store Y + accumulate per-channel stats
    int rowb = row0 + wv * 16 + fq * 4;
#pragma unroll
    for (int nf = 0; nf < 8; ++nf) {
        int col = nf * 16 + fr;
        float ps = 0.f, pq = 0.f;
#pragma unroll
        for (int j = 0; j < 4; ++j) {
            int r = rowb + j;
            if (r < M) {
                float v = tot[nf][j];
                Y[(size_t)r * DIM + col] = f2b(v);
                ps += v; pq += v * v;
            }
        }
        atomicAdd(&sh_s[col], ps);
        atomicAdd(&sh_q[col], pq);
    }
    __syncthreads();
    if (tid < 128) {
        atomicAdd(&stats[tid], sh_s[tid]);
        atomicAdd(&stats[DIM + tid], sh_q[tid]);
    }
}

// ============ bf16 MFMA GEMM for fc1/fc2 ============
__global__ __launch_bounds__(256) void mgemm_kernel(
    const ushort_t* __restrict__ A, const ushort_t* __restrict__ BT,
    const float* __restrict__ bias,
    float* __restrict__ Cf, ushort_t* __restrict__ Cb,
    int M, int K, int mode, int ncmask, int ldc)
{
    __shared__ ushort_t As[128 * 64];
    __shared__ ushort_t Bs[128 * 64];
    const int tid = threadIdx.x, lane = tid & 63, wid = tid >> 6;
    const int wm = wid >> 1, wn = wid & 1;
    const int row0 = blockIdx.x * 128, col0 = blockIdx.y * 128;
    const int fq = lane >> 4, fr = lane & 15;

    f32x4 acc[4][4] = {};

    for (int k0 = 0; k0 < K; k0 += 64) {
#pragma unroll
        for (int i = 0; i < 4; ++i) {
            int slotid = i * 256 + tid;
            int r = slotid >> 3, sl = slotid & 7;
            int sw = sl ^ (r & 7);
            int gra = row0 + r; if (gra >= M) gra = M - 1;
            __builtin_amdgcn_global_load_lds(
                (const __attribute__((address_space(1))) unsigned int*)(A + (size_t)gra * K + k0 + (sw << 3)),
                (__attribute__((address_space(3))) unsigned int*)((char*)As + slotid * 16), 16, 0, 0);
            __builtin_amdgcn_global_load_lds(
                (const __attribute__((address_space(1))) unsigned int*)(BT + (size_t)(col0 + r) * K + k0 + (sw << 3)),
                (__attribute__((address_space(3))) unsigned int*)((char*)Bs + slotid * 16), 16, 0, 0);
        }
        __syncthreads();
#pragma unroll
        for (int kk = 0; kk < 2; ++kk) {
            short8v a[4], b[4];
#pragma unroll
            for (int mf = 0; mf < 4; ++mf) {
                int ra = wm * 64 + mf * 16 + fr;
                int sa = ((kk * 4 + fq) ^ (ra & 7)) << 4;
                a[mf] = *(const short8v*)((const char*)As + ra * 128 + sa);
                int rb = wn * 64 + mf * 16 + fr;
                int sb = ((kk * 4 + fq) ^ (rb & 7)) << 4;
                b[mf] = *(const short8v*)((const char*)Bs + rb * 128 + sb);
            }
#pragma unroll
            for (int mf = 0; mf < 4; ++mf)
#pragma unroll
                for (int nf = 0; nf < 4; ++nf)
                    acc[mf][nf] = __builtin_amdgcn_mfma_f32_16x16x32_bf16(
                        a[mf], b[nf], acc[mf][nf], 0, 0, 0);
        }
        __syncthreads();
    }
#pragma unroll
    for (int mf = 0; mf < 4; ++mf) {
        int rowb = row0 + wm * 64 + mf * 16 + fq * 4;
#pragma unroll
        for (int nf = 0; nf < 4; ++nf) {
            int col = col0 + wn * 64 + nf * 16 + fr;
            f32x4 v = acc[mf][nf];
#pragma unroll
            for (int j = 0; j < 4; ++j) {
                int r = rowb + j;
                if (r >= M) continue;
                float val = v[j];
                if (mode == MODE_BF16R) {
                    Cb[(size_t)r * ldc + col] = f2b(fmaxf(val + bias[col], 0.f));
                } else {
                    if (col < ncmask) Cf[(size_t)r * ldc + col] = val + bias[col];
                }
            }
        }
    }
}

// ============ weight prep ============
__global__ void wprep_kernel(const float* __restrict__ W_s, const float* __restrict__ W_d,
                             const float* __restrict__ W_t, const float* __restrict__ W_i,
                             const float* __restrict__ W_fc1, const float* __restrict__ W_fc2,
                             const float* __restrict__ b_s, const float* __restrict__ b_d,
                             const float* __restrict__ b_t, const float* __restrict__ b_i,
                             ushort_t* __restrict__ WTl, ushort_t* __restrict__ WT1,
                             ushort_t* __restrict__ WT2, float* __restrict__ biascat)
{
    const int SZ_L = NLAYER * 512 * 128, SZ_1 = 256 * 256, SZ_2 = 128 * 256, SZ_B = NLAYER * 512;
    int idx = blockIdx.x * 256 + threadIdx.x;
    if (idx < SZ_L) {
        int l = idx / (512 * 128);
        int rem = idx - l * 512 * 128;
        int n = rem >> 7, k = rem & 127;
        float v;
        if (n < 128) v = W_i[((size_t)l * 128 + k) * 128 + n];
        else {
            int rel = (n - 128) >> 7, nn = (n - 128) & 127;
            const float* W = rel == 0 ? W_s : rel == 1 ? W_d : W_t;
            v = W[((size_t)l * 128 + k) * 128 + nn];
        }
        WTl[idx] = f2b(v);
    } else if (idx < SZ_L + SZ_1) {
        int j = idx - SZ_L;
        int n = j >> 8, k = j & 255;
        WT1[j] = f2b(W_fc1[(size_t)k * 256 + n]);
    } else if (idx < SZ_L + SZ_1 + SZ_2) {
        int j = idx - SZ_L - SZ_1;
        int n = j >> 8, k = j & 255;
        WT2[j] = f2b(n < 32 ? W_fc2[(size_t)k * 32 + n] : 0.f);
    } else if (idx < SZ_L + SZ_1 + SZ_2 + SZ_B) {
        int j = idx - SZ_L - SZ_1 - SZ_2;
        int l = j >> 9, rem = j & 511;
        int p = rem >> 7, c = rem & 127;
        const float* b = p == 0 ? b_i : p == 1 ? b_s : p == 2 ? b_d : b_t;
        biascat[j] = b[l * 128 + c];
    }
}

__global__ void xcvt_kernel(const float* __restrict__ x, uint_t* __restrict__ xb)
{
    long t = (long)blockIdx.x * 256 + threadIdx.x;
    if (t >= (long)N_NODES * DIM / 4) return;
    float4 v = *(const float4*)(x + t * 4);
    uint_t lo = (uint_t)f2b(v.x) | ((uint_t)f2b(v.y) << 16);
    uint_t hi = (uint_t)f2b(v.z) | ((uint_t)f2b(v.w) << 16);
    *(uint2*)(xb + t * 2) = make_uint2(lo, hi);
}

// ============ CSR build ============
__global__ void count_kernel(const int* __restrict__ ei, int* __restrict__ dega)
{
    int e = blockIdx.x * blockDim.x + threadIdx.x;
    if (e >= N_EDGES) return;
    atomicAdd(&dega[ei[N_EDGES + e]], 1);
}

__global__ void bsum_kernel(const int* __restrict__ dega, int* __restrict__ bsum)
{
    __shared__ int sh[256];
    int i = blockIdx.x * 256 + threadIdx.x;
    sh[threadIdx.x] = (i < N_NODES) ? dega[i] : 0;
    __syncthreads();
    for (int off = 128; off > 0; off >>= 1) {
        if (threadIdx.x < off) sh[threadIdx.x] += sh[threadIdx.x + off];
        __syncthreads();
    }
    if (threadIdx.x == 0) bsum[blockIdx.x] = sh[0];
}

__global__ void bscan_kernel(const int* __restrict__ bsum, int* __restrict__ boff,
                             int* __restrict__ rowptr)
{
    __shared__ int sh[256];
    int t = threadIdx.x;
    int v = (t < NBLK_SCAN) ? bsum[t] : 0;
    sh[t] = v;
    __syncthreads();
    for (int off = 1; off < 256; off <<= 1) {
        int u = (t >= off) ? sh[t - off] : 0;
        __syncthreads();
        sh[t] += u;
        __syncthreads();
    }
    if (t < NBLK_SCAN) boff[t] = sh[t] - v;
    if (t == 255) rowptr[N_NODES] = sh[255];
}

__global__ void rowptr_kernel(const int* __restrict__ dega, const int* __restrict__ boff,
                              int* __restrict__ rowptr, int* __restrict__ cursor)
{
    __shared__ int sh[256];
    int i = blockIdx.x * 256 + threadIdx.x;
    int t = threadIdx.x;
    int v = (i < N_NODES) ? dega[i] : 0;
    sh[t] = v;
    __syncthreads();
    for (int off = 1; off < 256; off <<= 1) {
        int u = (t >= off) ? sh[t - off] : 0;
        __syncthreads();
        sh[t] += u;
        __syncthreads();
    }
    if (i < N_NODES) {
        int e = boff[blockIdx.x] + sh[t] - v;
        rowptr[i] = e;
        cursor[i] = e;
    }
}

__global__ void fillpk_kernel(const int* __restrict__ ei, const int* __restrict__ ea,
                              int* __restrict__ cursor, uint_t* __restrict__ csr_pk)
{
    int e = blockIdx.x * blockDim.x + threadIdx.x;
    if (e >= N_EDGES) return;
    int r = ei[e], c = ei[N_EDGES + e];
    uint_t bits = (uint_t)(ea[e * 3 + 0] == 1) | ((uint_t)(ea[e * 3 + 1] == 1) << 1)
                | ((uint_t)(ea[e * 3 + 2] == 1) << 2);
    int slot = atomicAdd(&cursor[c], 1);
    csr_pk[slot] = (uint_t)r | (bits << 16);
}

__global__ void dinvseg_kernel(const int* __restrict__ rowptr, const uint_t* __restrict__ csr_pk,
                               float4* __restrict__ dinv4)
{
    int n = blockIdx.x * blockDim.x + threadIdx.x;
    if (n >= N_NODES) return;
    int p0 = rowptr[n], p1 = rowptr[n + 1];
    int d0 = 0, d1 = 0, d2 = 0;
    for (int p = p0; p < p1; ++p) {
        uint_t b = csr_pk[p] >> 16;
        d0 += b & 1; d1 += (b >> 1) & 1; d2 += (b >> 2) & 1;
    }
    float4 o;
    o.x = d0 ? rsqrtf((float)d0) : 0.f;
    o.y = d1 ? rsqrtf((float)d1) : 0.f;
    o.z = d2 ? rsqrtf((float)d2) : 0.f;
    o.w = 0.f;
    dinv4[n] = o;
}

__global__ void normfill_kernel(const int* __restrict__ rowptr, const uint_t* __restrict__ csr_pk,
                                const float4* __restrict__ dinv4, float4* __restrict__ nrm)
{
    int n = blockIdx.x * blockDim.x + threadIdx.x;
    if (n >= N_NODES) return;
    int p0 = rowptr[n], p1 = rowptr[n + 1];
    float4 dc = dinv4[n];
    for (int p = p0; p < p1; ++p) {
        uint_t pk = csr_pk[p];
        uint_t src = pk & 0xffffu, b = pk >> 16;
        float4 ds = dinv4[src];
        float4 m;
        m.x = (b & 1) ? ds.x * dc.x : 0.f;
        m.y = (b & 2) ? ds.y * dc.y : 0.f;
        m.z = (b & 4) ? ds.z * dc.z : 0.f;
        m.w = __uint_as_float(src);
        nrm[p] = m;
    }
}

// ============ gatherx: 2 nodes per wave (32 lanes, 4 ch/lane), 4-edge unroll ============
__global__ __launch_bounds__(256) void gatherx_kernel(
    const ushort_t* __restrict__ Xb, const int* __restrict__ rowptr,
    const float4* __restrict__ nrm, ushort_t* __restrict__ Agg)
{
    int wv = threadIdx.x >> 6, lane = threadIdx.x & 63;
    int half = lane >> 5, hl = lane & 31;
    int n = blockIdx.x * 8 + wv * 2 + half;
    if (n >= N_NODES) return;
    int p0 = rowptr[n], p1 = rowptr[n + 1];
    const char* xbase = (const char*)Xb + (hl << 3);   // 4 channels/lane (8B)
    float c0[4] = {}, c1[4] = {}, c2[4] = {};

    for (int p = p0; p < p1; p += 4) {
        float4 m[4];
        uint2 xv[4];
#pragma unroll
        for (int u = 0; u < 4; ++u)
            m[u] = (p + u < p1) ? nrm[p + u] : make_float4(0.f, 0.f, 0.f, 0.f);
#pragma unroll
        for (int u = 0; u < 4; ++u)
            xv[u] = *(const uint2*)(xbase + ((size_t)__float_as_uint(m[u].w) << 8));
#pragma unroll
        for (int u = 0; u < 4; ++u) {
            float x0 = blo(xv[u].x), x1 = bhi(xv[u].x), x2 = blo(xv[u].y), x3 = bhi(xv[u].y);
            c0[0] = fmaf(m[u].x, x0, c0[0]); c0[1] = fmaf(m[u].x, x1, c0[1]);
            c0[2] = fmaf(m[u].x, x2, c0[2]); c0[3] = fmaf(m[u].x, x3, c0[3]);
            c1[0] = fmaf(m[u].y, x0, c1[0]); c1[1] = fmaf(m[u].y, x1, c1[1]);
            c1[2] = fmaf(m[u].y, x2, c1[2]); c1[3] = fmaf(m[u].y, x3, c1[3]);
            c2[0] = fmaf(m[u].z, x0, c2[0]); c2[1] = fmaf(m[u].z, x1, c2[1]);
            c2[2] = fmaf(m[u].z, x2, c2[2]); c2[3] = fmaf(m[u].z, x3, c2[3]);
        }
    }
    char* ab = (char*)Agg + (size_t)n * 768 + (hl << 3);
    uint2 o0 = { (uint_t)f2b(c0[0]) | ((uint_t)f2b(c0[1]) << 16),
                 (uint_t)f2b(c0[2]) | ((uint_t)f2b(c0[3]) << 16) };
    uint2 o1 = { (uint_t)f2b(c1[0]) | ((uint_t)f2b(c1[1]) << 16),
                 (uint_t)f2b(c1[2]) | ((uint_t)f2b(c1[3]) << 16) };
    uint2 o2 = { (uint_t)f2b(c2[0]) | ((uint_t)f2b(c2[1]) << 16),
                 (uint_t)f2b(c2[2]) | ((uint_t)f2b(c2[3]) << 16) };
    *(uint2*)(ab)       = o0;
    *(uint2*)(ab + 256) = o1;
    *(uint2*)(ab + 512) = o2;
}

// ============ BN apply ============
__global__ void bn_apply_kernel(const ushort_t* __restrict__ Y, const float* __restrict__ stats,
                                const float* __restrict__ gamma, const float* __restrict__ beta,
                                ushort_t* __restrict__ Xb)
{
    long t = (long)blockIdx.x * 256 + threadIdx.x;      // one uint = 2 channels
    if (t >= (long)N_NODES * DIM / 2) return;
    int ch = (int)(t & 63) * 2;
    const float invN = 1.f / (float)N_NODES;
    uint_t yv = ((const uint_t*)Y)[t];
    uint_t o = 0;
#pragma unroll
    for (int k = 0; k < 2; ++k) {
        int c = ch + k;
        float mu = stats[c] * invN;
        float var = stats[DIM + c] * invN - mu * mu;
        float inv = rsqrtf(var + BN_EPS);
        float y = (k == 0 ? blo(yv) : bhi(yv));
        float v = fmaxf((y - mu) * inv * gamma[c] + beta[c], 0.f);
        o |= ((uint_t)f2b(v)) << (k * 16);
    }
    ((uint_t*)Xb)[t] = o;
}

// ============ group boundaries + pool + concat ============
__global__ void grp_kernel(const int* __restrict__ batch, int* __restrict__ grp_start)
{
    int n = blockIdx.x * blockDim.x + threadIdx.x;
    if (n >= N_NODES) return;
    int b = batch[n];
    if (n == 0) { for (int g = 0; g <= b; ++g) grp_start[g] = 0; }
    else {
        int pb = batch[n - 1];
        for (int g = pb + 1; g <= b; ++g) grp_start[g] = n;
    }
    if (n == N_NODES - 1) { for (int g = b + 1; g <= NGRAPH; ++g) grp_start[g] = N_NODES; }
}

__global__ __launch_bounds__(128) void pool_kernel(const ushort_t* __restrict__ Xb,
                                                   const int* __restrict__ grp_start,
                                                   float* __restrict__ pooled)
{
    int g = blockIdx.x, ch = threadIdx.x;
    int r0 = grp_start[g], r1 = grp_start[g + 1];
    float s = 0.f;
    for (int r = r0; r < r1; ++r) s += b2f(Xb[(size_t)r * DIM + ch]);
    pooled[(size_t)g * DIM + ch] = s;
}

__global__ void concat_kernel(const ushort_t* __restrict__ Xb, const float* __restrict__ pooled,
                              const int* __restrict__ batch, ushort_t* __restrict__ Cat)
{
    long t = (long)blockIdx.x * blockDim.x + threadIdx.x;
    if (t >= (long)N_NODES * 32) return;
    int n = (int)(t >> 5), c8 = (int)(t & 31);
    if (c8 < 16) {
        *(uint4*)(Cat + (size_t)n * 256 + c8 * 8) =
            *(const uint4*)(Xb + (size_t)n * DIM + c8 * 8);
    } else {
        const float* ps = pooled + (size_t)batch[n] * DIM + (c8 - 16) * 8;
        float4 v0 = *(const float4*)ps, v1 = *(const float4*)(ps + 4);
        uint4 o;
        o.x = (uint_t)f2b(v0.x) | ((uint_t)f2b(v0.y) << 16);
        o.y = (uint_t)f2b(v0.z) | ((uint_t)f2b(v0.w) << 16);
        o.z = (uint_t)f2b(v1.x) | ((uint_t)f2b(v1.y) << 16);
        o.w = (uint_t)f2b(v1.z) | ((uint_t)f2b(v1.w) << 16);
        *(uint4*)(Cat + (size_t)n * 256 + c8 * 8) = o;
    }
}

extern "C" void kernel_launch(void* const* d_in, const int* in_sizes, int n_in,
                              void* d_out, int out_size, void* d_ws, size_t ws_size,
                              hipStream_t stream) {
    (void)in_sizes; (void)n_in; (void)out_size; (void)ws_size;
    const float* x_in = (const float*)d_in[0];
    const int* edge_index = (const int*)d_in[1];
    const int* edge_attr  = (const int*)d_in[2];
    const int* batch      = (const int*)d_in[3];
    const float* W_s   = (const float*)d_in[4];
    const float* b_s   = (const float*)d_in[5];
    const float* W_d   = (const float*)d_in[6];
    const float* b_d   = (const float*)d_in[7];
    const float* W_t   = (const float*)d_in[8];
    const float* b_t   = (const float*)d_in[9];
    const float* W_i   = (const float*)d_in[10];
    const float* b_i   = (const float*)d_in[11];
    const float* gamma = (const float*)d_in[12];
    const float* beta  = (const float*)d_in[13];
    const float* W_fc1 = (const float*)d_in[14];
    const float* b_fc1 = (const float*)d_in[15];
    const float* W_fc2 = (const float*)d_in[16];
    const float* b_fc2 = (const float*)d_in[17];
    float* out = (float*)d_out;

    // ---- workspace layout ----
    char* ws = (char*)d_ws;
    size_t off = 0;
    auto alloc = [&](size_t bytes) { char* p = ws + off; off += (bytes + 255) & ~(size_t)255; return p; };
    int*   dega    = (int*)  alloc((size_t)N_NODES * 4);
    int*   rowptr  = (int*)  alloc((size_t)(N_NODES + 1) * 4);
    int*   cursor  = (int*)  alloc((size_t)N_NODES * 4);
    int*   bsum    = (int*)  alloc(256 * 4);
    int*   boff    = (int*)  alloc(256 * 4);
    int*   grp     = (int*)  alloc((size_t)(NGRAPH + 1) * 4);
    uint_t* csr_pk = (uint_t*)alloc((size_t)N_EDGES * 4);
    float4* dinv4  = (float4*)alloc((size_t)N_NODES * 16);
    float4* nrm    = (float4*)alloc((size_t)(N_EDGES + 8) * 16);
    float* stats   = (float*)alloc((size_t)NLAYER * 2 * DIM * 4);
    float* pooled  = (float*)alloc((size_t)NGRAPH * DIM * 4);
    float* biascat = (float*)alloc((size_t)NLAYER * 512 * 4);
    ushort_t* WTl  = (ushort_t*)alloc((size_t)NLAYER * 512 * 128 * 2);
    ushort_t* WT1  = (ushort_t*)alloc((size_t)256 * 256 * 2);
    ushort_t* WT2  = (ushort_t*)alloc((size_t)128 * 256 * 2);
    ushort_t* Xb   = (ushort_t*)alloc((size_t)N_NODES * DIM * 2);
    ushort_t* Yb   = (ushort_t*)alloc((size_t)N_NODES * DIM * 2);
    ushort_t* Agg  = (ushort_t*)alloc((size_t)N_NODES * 384 * 2);
    ushort_t* Hidden = (ushort_t*)alloc((size_t)N_NODES * HMLP * 2);
    ushort_t* Cat  = Agg;

    const long ND = (long)N_NODES * DIM;
    dim3 blk256(256);
    dim3 grid_n((unsigned)((N_NODES + 255) / 256));
    dim3 grid_edges((unsigned)((N_EDGES + 255) / 256));
    const int MB128 = (N_NODES + 127) / 128;
    const int MB64  = (N_NODES + 63) / 64;

    // ---- prep ----
    hipMemsetAsync(dega, 0, (size_t)N_NODES * 4, stream);
    hipMemsetAsync(stats, 0, (size_t)NLAYER * 2 * DIM * 4, stream);
    count_kernel<<<grid_edges, blk256, 0, stream>>>(edge_index, dega);
    bsum_kernel<<<dim3(NBLK_SCAN), blk256, 0, stream>>>(dega, bsum);
    bscan_kernel<<<dim3(1), blk256, 0, stream>>>(bsum, boff, rowptr);
    rowptr_kernel<<<dim3(NBLK_SCAN), blk256, 0, stream>>>(dega, boff, rowptr, cursor);
    fillpk_kernel<<<grid_edges, blk256, 0, stream>>>(edge_index, edge_attr, cursor, csr_pk);
    dinvseg_kernel<<<grid_n, blk256, 0, stream>>>(rowptr, csr_pk, dinv4);
    normfill_kernel<<<grid_n, blk256, 0, stream>>>(rowptr, csr_pk, dinv4, nrm);
    grp_kernel<<<grid_n, blk256, 0, stream>>>(batch, grp);
    wprep_kernel<<<dim3((NLAYER * 512 * 128 + 256 * 256 + 128 * 256 + NLAYER * 512 + 255) / 256),
                   blk256, 0, stream>>>(
        W_s, W_d, W_t, W_i, W_fc1, W_fc2, b_s, b_d, b_t, b_i, WTl, WT1, WT2, biascat);
    xcvt_kernel<<<dim3((unsigned)((ND / 4 + 255) / 256)), blk256, 0, stream>>>(x_in, (uint_t*)Xb);

    for (int l = 0; l < NLAYER; ++l) {
        gatherx_kernel<<<dim3((N_NODES + 7) / 8), blk256, 0, stream>>>(Xb, rowptr, nrm, Agg);
        flgemm_kernel<<<dim3(MB64), blk256, 0, stream>>>(
            Xb, Agg, WTl + (size_t)l * 512 * 128, biascat + (size_t)l * 512, Yb,
            stats + (size_t)l * 2 * DIM, N_NODES);
        bn_apply_kernel<<<dim3((unsigned)((ND / 2 + 255) / 256)), blk256, 0, stream>>>(
            Yb, stats + (size_t)l * 2 * DIM, gamma + (size_t)l * DIM, beta + (size_t)l * DIM, Xb);
    }

    // ---- pool + concat + MLP ----
    pool_kernel<<<dim3(NGRAPH), dim3(DIM), 0, stream>>>(Xb, grp, pooled);
    concat_kernel<<<dim3((unsigned)((N_NODES * 32 + 255) / 256)), blk256, 0, stream>>>(
        Xb, pooled, batch, Cat);
    mgemm_kernel<<<dim3(MB128, 2), blk256, 0, stream>>>(
        Cat, WT1, b_fc1, nullptr, Hidden, N_NODES, 2 * DIM, MODE_BF16R, 0, HMLP);
    mgemm_kernel<<<dim3(MB128, 1), blk256, 0, stream>>>(
        Hidden, WT2, b_fc2, out, nullptr, N_NODES, HMLP, MODE_F32, NCLS, NCLS);
}

// Round 11
// 430.004 us; speedup vs baseline: 1.0817x; 1.0817x over previous
//
#include <hip/hip_runtime.h>
#include <hip/hip_bf16.h>

#define N_NODES 50000
#define N_EDGES 600000
#define DIM     128
#define HMLP    256
#define NCLS    32
#define NGRAPH  512
#define NLAYER  3
#define BN_EPS  1e-5f
#define NBLK_SCAN ((N_NODES + 255) / 256)

typedef unsigned short ushort_t;
typedef unsigned int uint_t;
typedef __attribute__((ext_vector_type(8))) short short8v;
typedef __attribute__((ext_vector_type(4))) float f32x4;

#define MODE_BF16R 1
#define MODE_F32   2

__device__ __forceinline__ ushort_t f2b(float v) {
    __hip_bfloat16 h = __float2bfloat16(v);
    return *reinterpret_cast<ushort_t*>(&h);
}
__device__ __forceinline__ float b2f(ushort_t u) {
    __hip_bfloat16 h = *reinterpret_cast<__hip_bfloat16*>(&u);
    return __bfloat162float(h);
}
__device__ __forceinline__ float blo(uint_t h) { return b2f((ushort_t)(h & 0xffffu)); }
__device__ __forceinline__ float bhi(uint_t h) { return b2f((ushort_t)(h >> 16)); }

// ============ fused layer GEMM + BN-stats, T3 2-phase double-buffered ============
// 128-row tile, 256 thr / 4 waves, each wave 32 rows x 128 cols.
// 8 phases = 4 branches x 2 K-chunks; stage phase t+1 while computing phase t.
__global__ __launch_bounds__(256) void flgemm_kernel(
    const ushort_t* __restrict__ Xp,   // [N][128]
    const ushort_t* __restrict__ Agg,  // [N][384]
    const ushort_t* __restrict__ WT,   // [512][128]
    const float* __restrict__ biascat, // [512]
    ushort_t* __restrict__ Y,
    float* __restrict__ stats,         // [256]: sum | sumsq
    int M)
{
    __shared__ char lds[2 * 32768];    // per buf: As 128x64 (16KB) + Bs 128x64 (16KB)
    __shared__ float sh_s[128];
    __shared__ float sh_q[128];
    const int tid = threadIdx.x, lane = tid & 63, wv = tid >> 6;
    const int row0 = blockIdx.x * 128;
    const int fq = lane >> 4, fr = lane & 15;

    if (tid < 128) { sh_s[tid] = 0.f; sh_q[tid] = 0.f; }

    // stage phase t (p = t>>1, k0 = (t&1)*64) into buffer buf
    auto stage = [&](int t, int buf) {
        int p = t >> 1, k0 = (t & 1) * 64;
        const ushort_t* Ap = (p == 0) ? (Xp + (size_t)row0 * 128)
                                      : (Agg + (size_t)row0 * 384 + (p - 1) * 128);
        const int lda = (p == 0) ? 128 : 384;
        const ushort_t* Bp = WT + (size_t)p * 128 * 128;
        char* Asb = lds + buf * 32768;
        char* Bsb = Asb + 16384;
#pragma unroll
        for (int i = 0; i < 4; ++i) {              // A: 128 rows x 8 slots = 1024
            int sid = i * 256 + tid;
            int r = sid >> 3, sl = sid & 7, sw = sl ^ (r & 7);
            int rr = (row0 + r < M) ? r : (M - 1 - row0);
            __builtin_amdgcn_global_load_lds(
                (const __attribute__((address_space(1))) unsigned int*)(Ap + (size_t)rr * lda + k0 + (sw << 3)),
                (__attribute__((address_space(3))) unsigned int*)(Asb + sid * 16), 16, 0, 0);
        }
#pragma unroll
        for (int i = 0; i < 4; ++i) {              // B: 128 rows x 8 slots = 1024
            int sid = i * 256 + tid;
            int r = sid >> 3, sl = sid & 7, sw = sl ^ (r & 7);
            __builtin_amdgcn_global_load_lds(
                (const __attribute__((address_space(1))) unsigned int*)(Bp + (size_t)r * 128 + k0 + (sw << 3)),
                (__attribute__((address_space(3))) unsigned int*)(Bsb + sid * 16), 16, 0, 0);
        }
    };

    f32x4 tot[2][8] = {};
    f32x4 acc[2][8] = {};

    // prologue: buf0 = phase 0
    stage(0, 0);
    asm volatile("s_waitcnt vmcnt(0)" ::: "memory");
    __builtin_amdgcn_s_barrier();

    int cur = 0;
#pragma unroll
    for (int t = 0; t < 8; ++t) {
        if (t < 7) stage(t + 1, cur ^ 1);          // prefetch next phase
        const char* Asb = lds + cur * 32768;
        const char* Bsb = Asb + 16384;
#pragma unroll
        for (int kk = 0; kk < 2; ++kk) {
            short8v a[2], b[8];
#pragma unroll
            for (int mf = 0; mf < 2; ++mf) {
                int ra = wv * 32 + mf * 16 + fr;
                a[mf] = *(const short8v*)(Asb + ra * 128 + (((kk * 4 + fq) ^ (ra & 7)) << 4));
            }
#pragma unroll
            for (int nf = 0; nf < 8; ++nf) {
                int rb = nf * 16 + fr;
                b[nf] = *(const short8v*)(Bsb + rb * 128 + (((kk * 4 + fq) ^ (rb & 7)) << 4));
            }
#pragma unroll
            for (int mf = 0; mf < 2; ++mf)
#pragma unroll
                for (int nf = 0; nf < 8; ++nf)
                    acc[mf][nf] = __builtin_amdgcn_mfma_f32_16x16x32_bf16(
                        a[mf], b[nf], acc[mf][nf], 0, 0, 0);
        }
        if (t & 1) {                               // branch complete: fold into tot
            int p = t >> 1;
#pragma unroll
            for (int nf = 0; nf < 8; ++nf) {
                float bv = biascat[p * 128 + nf * 16 + fr];
#pragma unroll
                for (int mf = 0; mf < 2; ++mf) {
#pragma unroll
                    for (int j = 0; j < 4; ++j)
                        tot[mf][nf][j] += fmaxf(acc[mf][nf][j] + bv, 0.f);
                    acc[mf][nf] = f32x4{0.f, 0.f, 0.f, 0.f};
                }
            }
        }
        asm volatile("s_waitcnt vmcnt(0)" ::: "memory");   // staged loads landed, LDS reads done
        __builtin_amdgcn_s_barrier();
        cur ^= 1;
    }

    // store Y + per-channel stats
#pragma unroll
    for (int nf = 0; nf < 8; ++nf) {
        int col = nf * 16 + fr;
        float ps = 0.f, pq = 0.f;
#pragma unroll
        for (int mf = 0; mf < 2; ++mf) {
            int rowb = row0 + wv * 32 + mf * 16 + fq * 4;
#pragma unroll
            for (int j = 0; j < 4; ++j) {
                int r = rowb + j;
                if (r < M) {
                    float v = tot[mf][nf][j];
                    Y[(size_t)r * DIM + col] = f2b(v);
                    ps += v; pq += v * v;
                }
            }
        }
        atomicAdd(&sh_s[col], ps);
        atomicAdd(&sh_q[col], pq);
    }
    __syncthreads();
    if (tid < 128) {
        atomicAdd(&stats[tid], sh_s[tid]);
        atomicAdd(&stats[DIM + tid], sh_q[tid]);
    }
}

// ============ bf16 MFMA GEMM for fc1/fc2 ============
__global__ __launch_bounds__(256) void mgemm_kernel(
    const ushort_t* __restrict__ A, const ushort_t* __restrict__ BT,
    const float* __restrict__ bias,
    float* __restrict__ Cf, ushort_t* __restrict__ Cb,
    int M, int K, int mode, int ncmask, int ldc)
{
    __shared__ ushort_t As[128 * 64];
    __shared__ ushort_t Bs[128 * 64];
    const int tid = threadIdx.x, lane = tid & 63, wid = tid >> 6;
    const int wm = wid >> 1, wn = wid & 1;
    const int row0 = blockIdx.x * 128, col0 = blockIdx.y * 128;
    const int fq = lane >> 4, fr = lane & 15;

    f32x4 acc[4][4] = {};

    for (int k0 = 0; k0 < K; k0 += 64) {
#pragma unroll
        for (int i = 0; i < 4; ++i) {
            int slotid = i * 256 + tid;
            int r = slotid >> 3, sl = slotid & 7;
            int sw = sl ^ (r & 7);
            int gra = row0 + r; if (gra >= M) gra = M - 1;
            __builtin_amdgcn_global_load_lds(
                (const __attribute__((address_space(1))) unsigned int*)(A + (size_t)gra * K + k0 + (sw << 3)),
                (__attribute__((address_space(3))) unsigned int*)((char*)As + slotid * 16), 16, 0, 0);
            __builtin_amdgcn_global_load_lds(
                (const __attribute__((address_space(1))) unsigned int*)(BT + (size_t)(col0 + r) * K + k0 + (sw << 3)),
                (__attribute__((address_space(3))) unsigned int*)((char*)Bs + slotid * 16), 16, 0, 0);
        }
        __syncthreads();
#pragma unroll
        for (int kk = 0; kk < 2; ++kk) {
            short8v a[4], b[4];
#pragma unroll
            for (int mf = 0; mf < 4; ++mf) {
                int ra = wm * 64 + mf * 16 + fr;
                int sa = ((kk * 4 + fq) ^ (ra & 7)) << 4;
                a[mf] = *(const short8v*)((const char*)As + ra * 128 + sa);
                int rb = wn * 64 + mf * 16 + fr;
                int sb = ((kk * 4 + fq) ^ (rb & 7)) << 4;
                b[mf] = *(const short8v*)((const char*)Bs + rb * 128 + sb);
            }
#pragma unroll
            for (int mf = 0; mf < 4; ++mf)
#pragma unroll
                for (int nf = 0; nf < 4; ++nf)
                    acc[mf][nf] = __builtin_amdgcn_mfma_f32_16x16x32_bf16(
                        a[mf], b[nf], acc[mf][nf], 0, 0, 0);
        }
        __syncthreads();
    }
#pragma unroll
    for (int mf = 0; mf < 4; ++mf) {
        int rowb = row0 + wm * 64 + mf * 16 + fq * 4;
#pragma unroll
        for (int nf = 0; nf < 4; ++nf) {
            int col = col0 + wn * 64 + nf * 16 + fr;
            f32x4 v = acc[mf][nf];
#pragma unroll
            for (int j = 0; j < 4; ++j) {
                int r = rowb + j;
                if (r >= M) continue;
                float val = v[j];
                if (mode == MODE_BF16R) {
                    Cb[(size_t)r * ldc + col] = f2b(fmaxf(val + bias[col], 0.f));
                } else {
                    if (col < ncmask) Cf[(size_t)r * ldc + col] = val + bias[col];
                }
            }
        }
    }
}

// ============ weight prep ============
__global__ void wprep_kernel(const float* __restrict__ W_s, const float* __restrict__ W_d,
                             const float* __restrict__ W_t, const float* __restrict__ W_i,
                             const float* __restrict__ W_fc1, const float* __restrict__ W_fc2,
                             const float* __restrict__ b_s, const float* __restrict__ b_d,
                             const float* __restrict__ b_t, const float* __restrict__ b_i,
                             ushort_t* __restrict__ WTl, ushort_t* __restrict__ WT1,
                             ushort_t* __restrict__ WT2, float* __restrict__ biascat)
{
    const int SZ_L = NLAYER * 512 * 128, SZ_1 = 256 * 256, SZ_2 = 128 * 256, SZ_B = NLAYER * 512;
    int idx = blockIdx.x * 256 + threadIdx.x;
    if (idx < SZ_L) {
        int l = idx / (512 * 128);
        int rem = idx - l * 512 * 128;
        int n = rem >> 7, k = rem & 127;
        float v;
        if (n < 128) v = W_i[((size_t)l * 128 + k) * 128 + n];
        else {
            int rel = (n - 128) >> 7, nn = (n - 128) & 127;
            const float* W = rel == 0 ? W_s : rel == 1 ? W_d : W_t;
            v = W[((size_t)l * 128 + k) * 128 + nn];
        }
        WTl[idx] = f2b(v);
    } else if (idx < SZ_L + SZ_1) {
        int j = idx - SZ_L;
        int n = j >> 8, k = j & 255;
        WT1[j] = f2b(W_fc1[(size_t)k * 256 + n]);
    } else if (idx < SZ_L + SZ_1 + SZ_2) {
        int j = idx - SZ_L - SZ_1;
        int n = j >> 8, k = j & 255;
        WT2[j] = f2b(n < 32 ? W_fc2[(size_t)k * 32 + n] : 0.f);
    } else if (idx < SZ_L + SZ_1 + SZ_2 + SZ_B) {
        int j = idx - SZ_L - SZ_1 - SZ_2;
        int l = j >> 9, rem = j & 511;
        int p = rem >> 7, c = rem & 127;
        const float* b = p == 0 ? b_i : p == 1 ? b_s : p == 2 ? b_d : b_t;
        biascat[j] = b[l * 128 + c];
    }
}

__global__ void xcvt_kernel(const float* __restrict__ x, uint_t* __restrict__ xb)
{
    long t = (long)blockIdx.x * 256 + threadIdx.x;
    if (t >= (long)N_NODES * DIM / 4) return;
    float4 v = *(const float4*)(x + t * 4);
    uint_t lo = (uint_t)f2b(v.x) | ((uint_t)f2b(v.y) << 16);
    uint_t hi = (uint_t)f2b(v.z) | ((uint_t)f2b(v.w) << 16);
    *(uint2*)(xb + t * 2) = make_uint2(lo, hi);
}

// ============ CSR build ============
__global__ void count_kernel(const int* __restrict__ ei, int* __restrict__ dega)
{
    int e = blockIdx.x * blockDim.x + threadIdx.x;
    if (e >= N_EDGES) return;
    atomicAdd(&dega[ei[N_EDGES + e]], 1);
}

__global__ void bsum_kernel(const int* __restrict__ dega, int* __restrict__ bsum)
{
    __shared__ int sh[256];
    int i = blockIdx.x * 256 + threadIdx.x;
    sh[threadIdx.x] = (i < N_NODES) ? dega[i] : 0;
    __syncthreads();
    for (int off = 128; off > 0; off >>= 1) {
        if (threadIdx.x < off) sh[threadIdx.x] += sh[threadIdx.x + off];
        __syncthreads();
    }
    if (threadIdx.x == 0) bsum[blockIdx.x] = sh[0];
}

__global__ void bscan_kernel(const int* __restrict__ bsum, int* __restrict__ boff,
                             int* __restrict__ rowptr)
{
    __shared__ int sh[256];
    int t = threadIdx.x;
    int v = (t < NBLK_SCAN) ? bsum[t] : 0;
    sh[t] = v;
    __syncthreads();
    for (int off = 1; off < 256; off <<= 1) {
        int u = (t >= off) ? sh[t - off] : 0;
        __syncthreads();
        sh[t] += u;
        __syncthreads();
    }
    if (t < NBLK_SCAN) boff[t] = sh[t] - v;
    if (t == 255) rowptr[N_NODES] = sh[255];
}

__global__ void rowptr_kernel(const int* __restrict__ dega, const int* __restrict__ boff,
                              int* __restrict__ rowptr, int* __restrict__ cursor)
{
    __shared__ int sh[256];
    int i = blockIdx.x * 256 + threadIdx.x;
    int t = threadIdx.x;
    int v = (i < N_NODES) ? dega[i] : 0;
    sh[t] = v;
    __syncthreads();
    for (int off = 1; off < 256; off <<= 1) {
        int u = (t >= off) ? sh[t - off] : 0;
        __syncthreads();
        sh[t] += u;
        __syncthreads();
    }
    if (i < N_NODES) {
        int e = boff[blockIdx.x] + sh[t] - v;
        rowptr[i] = e;
        cursor[i] = e;
    }
}

__global__ void fillpk_kernel(const int* __restrict__ ei, const int* __restrict__ ea,
                              int* __restrict__ cursor, uint_t* __restrict__ csr_pk)
{
    int e = blockIdx.x * blockDim.x + threadIdx.x;
    if (e >= N_EDGES) return;
    int r = ei[e], c = ei[N_EDGES + e];
    uint_t bits = (uint_t)(ea[e * 3 + 0] == 1) | ((uint_t)(ea[e * 3 + 1] == 1) << 1)
                | ((uint_t)(ea[e * 3 + 2] == 1) << 2);
    int slot = atomicAdd(&cursor[c], 1);
    csr_pk[slot] = (uint_t)r | (bits << 16);
}

__global__ void dinvseg_kernel(const int* __restrict__ rowptr, const uint_t* __restrict__ csr_pk,
                               float4* __restrict__ dinv4)
{
    int n = blockIdx.x * blockDim.x + threadIdx.x;
    if (n >= N_NODES) return;
    int p0 = rowptr[n], p1 = rowptr[n + 1];
    int d0 = 0, d1 = 0, d2 = 0;
    for (int p = p0; p < p1; ++p) {
        uint_t b = csr_pk[p] >> 16;
        d0 += b & 1; d1 += (b >> 1) & 1; d2 += (b >> 2) & 1;
    }
    float4 o;
    o.x = d0 ? rsqrtf((float)d0) : 0.f;
    o.y = d1 ? rsqrtf((float)d1) : 0.f;
    o.z = d2 ? rsqrtf((float)d2) : 0.f;
    o.w = 0.f;
    dinv4[n] = o;
}

__global__ void normfill_kernel(const int* __restrict__ rowptr, const uint_t* __restrict__ csr_pk,
                                const float4* __restrict__ dinv4, float4* __restrict__ nrm)
{
    int n = blockIdx.x * blockDim.x + threadIdx.x;
    if (n >= N_NODES) return;
    int p0 = rowptr[n], p1 = rowptr[n + 1];
    float4 dc = dinv4[n];
    for (int p = p0; p < p1; ++p) {
        uint_t pk = csr_pk[p];
        uint_t src = pk & 0xffffu, b = pk >> 16;
        float4 ds = dinv4[src];
        float4 m;
        m.x = (b & 1) ? ds.x * dc.x : 0.f;
        m.y = (b & 2) ? ds.y * dc.y : 0.f;
        m.z = (b & 4) ? ds.z * dc.z : 0.f;
        m.w = __uint_as_float(src);
        nrm[p] = m;
    }
}

// ============ gatherx: 2 nodes per wave (32 lanes, 4 ch/lane), 4-edge unroll ============
__global__ __launch_bounds__(256) void gatherx_kernel(
    const ushort_t* __restrict__ Xb, const int* __restrict__ rowptr,
    const float4* __restrict__ nrm, ushort_t* __restrict__ Agg)
{
    int wv = threadIdx.x >> 6, lane = threadIdx.x & 63;
    int half = lane >> 5, hl = lane & 31;
    int n = blockIdx.x * 8 + wv * 2 + half;
    if (n >= N_NODES) return;
    int p0 = rowptr[n], p1 = rowptr[n + 1];
    const char* xbase = (const char*)Xb + (hl << 3);   // 4 channels/lane (8B)
    float c0[4] = {}, c1[4] = {}, c2[4] = {};

    for (int p = p0; p < p1; p += 4) {
        float4 m[4];
        uint2 xv[4];
#pragma unroll
        for (int u = 0; u < 4; ++u)
            m[u] = (p + u < p1) ? nrm[p + u] : make_float4(0.f, 0.f, 0.f, 0.f);
#pragma unroll
        for (int u = 0; u < 4; ++u)
            xv[u] = *(const uint2*)(xbase + ((size_t)__float_as_uint(m[u].w) << 8));
#pragma unroll
        for (int u = 0; u < 4; ++u) {
            float x0 = blo(xv[u].x), x1 = bhi(xv[u].x), x2 = blo(xv[u].y), x3 = bhi(xv[u].y);
            c0[0] = fmaf(m[u].x, x0, c0[0]); c0[1] = fmaf(m[u].x, x1, c0[1]);
            c0[2] = fmaf(m[u].x, x2, c0[2]); c0[3] = fmaf(m[u].x, x3, c0[3]);
            c1[0] = fmaf(m[u].y, x0, c1[0]); c1[1] = fmaf(m[u].y, x1, c1[1]);
            c1[2] = fmaf(m[u].y, x2, c1[2]); c1[3] = fmaf(m[u].y, x3, c1[3]);
            c2[0] = fmaf(m[u].z, x0, c2[0]); c2[1] = fmaf(m[u].z, x1, c2[1]);
            c2[2] = fmaf(m[u].z, x2, c2[2]); c2[3] = fmaf(m[u].z, x3, c2[3]);
        }
    }
    char* ab = (char*)Agg + (size_t)n * 768 + (hl << 3);
    uint2 o0 = { (uint_t)f2b(c0[0]) | ((uint_t)f2b(c0[1]) << 16),
                 (uint_t)f2b(c0[2]) | ((uint_t)f2b(c0[3]) << 16) };
    uint2 o1 = { (uint_t)f2b(c1[0]) | ((uint_t)f2b(c1[1]) << 16),
                 (uint_t)f2b(c1[2]) | ((uint_t)f2b(c1[3]) << 16) };
    uint2 o2 = { (uint_t)f2b(c2[0]) | ((uint_t)f2b(c2[1]) << 16),
                 (uint_t)f2b(c2[2]) | ((uint_t)f2b(c2[3]) << 16) };
    *(uint2*)(ab)       = o0;
    *(uint2*)(ab + 256) = o1;
    *(uint2*)(ab + 512) = o2;
}

// ============ BN apply ============
__global__ void bn_apply_kernel(const ushort_t* __restrict__ Y, const float* __restrict__ stats,
                                const float* __restrict__ gamma, const float* __restrict__ beta,
                                ushort_t* __restrict__ Xb)
{
    long t = (long)blockIdx.x * 256 + threadIdx.x;      // one uint = 2 channels
    if (t >= (long)N_NODES * DIM / 2) return;
    int ch = (int)(t & 63) * 2;
    const float invN = 1.f / (float)N_NODES;
    uint_t yv = ((const uint_t*)Y)[t];
    uint_t o = 0;
#pragma unroll
    for (int k = 0; k < 2; ++k) {
        int c = ch + k;
        float mu = stats[c] * invN;
        float var = stats[DIM + c] * invN - mu * mu;
        float inv = rsqrtf(var + BN_EPS);
        float y = (k == 0 ? blo(yv) : bhi(yv));
        float v = fmaxf((y - mu) * inv * gamma[c] + beta[c], 0.f);
        o |= ((uint_t)f2b(v)) << (k * 16);
    }
    ((uint_t*)Xb)[t] = o;
}

// ============ group boundaries + pool + concat ============
__global__ void grp_kernel(const int* __restrict__ batch, int* __restrict__ grp_start)
{
    int n = blockIdx.x * blockDim.x + threadIdx.x;
    if (n >= N_NODES) return;
    int b = batch[n];
    if (n == 0) { for (int g = 0; g <= b; ++g) grp_start[g] = 0; }
    else {
        int pb = batch[n - 1];
        for (int g = pb + 1; g <= b; ++g) grp_start[g] = n;
    }
    if (n == N_NODES - 1) { for (int g = b + 1; g <= NGRAPH; ++g) grp_start[g] = N_NODES; }
}

__global__ __launch_bounds__(128) void pool_kernel(const ushort_t* __restrict__ Xb,
                                                   const int* __restrict__ grp_start,
                                                   float* __restrict__ pooled)
{
    int g = blockIdx.x, ch = threadIdx.x;
    int r0 = grp_start[g], r1 = grp_start[g + 1];
    float s = 0.f;
    for (int r = r0; r < r1; ++r) s += b2f(Xb[(size_t)r * DIM + ch]);
    pooled[(size_t)g * DIM + ch] = s;
}

__global__ void concat_kernel(const ushort_t* __restrict__ Xb, const float* __restrict__ pooled,
                              const int* __restrict__ batch, ushort_t* __restrict__ Cat)
{
    long t = (long)blockIdx.x * blockDim.x + threadIdx.x;
    if (t >= (long)N_NODES * 32) return;
    int n = (int)(t >> 5), c8 = (int)(t & 31);
    if (c8 < 16) {
        *(uint4*)(Cat + (size_t)n * 256 + c8 * 8) =
            *(const uint4*)(Xb + (size_t)n * DIM + c8 * 8);
    } else {
        const float* ps = pooled + (size_t)batch[n] * DIM + (c8 - 16) * 8;
        float4 v0 = *(const float4*)ps, v1 = *(const float4*)(ps + 4);
        uint4 o;
        o.x = (uint_t)f2b(v0.x) | ((uint_t)f2b(v0.y) << 16);
        o.y = (uint_t)f2b(v0.z) | ((uint_t)f2b(v0.w) << 16);
        o.z = (uint_t)f2b(v1.x) | ((uint_t)f2b(v1.y) << 16);
        o.w = (uint_t)f2b(v1.z) | ((uint_t)f2b(v1.w) << 16);
        *(uint4*)(Cat + (size_t)n * 256 + c8 * 8) = o;
    }
}

extern "C" void kernel_launch(void* const* d_in, const int* in_sizes, int n_in,
                              void* d_out, int out_size, void* d_ws, size_t ws_size,
                              hipStream_t stream) {
    (void)in_sizes; (void)n_in; (void)out_size; (void)ws_size;
    const float* x_in = (const float*)d_in[0];
    const int* edge_index = (const int*)d_in[1];
    const int* edge_attr  = (const int*)d_in[2];
    const int* batch      = (const int*)d_in[3];
    const float* W_s   = (const float*)d_in[4];
    const float* b_s   = (const float*)d_in[5];
    const float* W_d   = (const float*)d_in[6];
    const float* b_d   = (const float*)d_in[7];
    const float* W_t   = (const float*)d_in[8];
    const float* b_t   = (const float*)d_in[9];
    const float* W_i   = (const float*)d_in[10];
    const float* b_i   = (const float*)d_in[11];
    const float* gamma = (const float*)d_in[12];
    const float* beta  = (const float*)d_in[13];
    const float* W_fc1 = (const float*)d_in[14];
    const float* b_fc1 = (const float*)d_in[15];
    const float* W_fc2 = (const float*)d_in[16];
    const float* b_fc2 = (const float*)d_in[17];
    float* out = (float*)d_out;

    // ---- workspace layout ----
    char* ws = (char*)d_ws;
    size_t off = 0;
    auto alloc = [&](size_t bytes) { char* p = ws + off; off += (bytes + 255) & ~(size_t)255; return p; };
    int*   dega    = (int*)  alloc((size_t)N_NODES * 4);
    int*   rowptr  = (int*)  alloc((size_t)(N_NODES + 1) * 4);
    int*   cursor  = (int*)  alloc((size_t)N_NODES * 4);
    int*   bsum    = (int*)  alloc(256 * 4);
    int*   boff    = (int*)  alloc(256 * 4);
    int*   grp     = (int*)  alloc((size_t)(NGRAPH + 1) * 4);
    uint_t* csr_pk = (uint_t*)alloc((size_t)N_EDGES * 4);
    float4* dinv4  = (float4*)alloc((size_t)N_NODES * 16);
    float4* nrm    = (float4*)alloc((size_t)(N_EDGES + 8) * 16);
    float* stats   = (float*)alloc((size_t)NLAYER * 2 * DIM * 4);
    float* pooled  = (float*)alloc((size_t)NGRAPH * DIM * 4);
    float* biascat = (float*)alloc((size_t)NLAYER * 512 * 4);
    ushort_t* WTl  = (ushort_t*)alloc((size_t)NLAYER * 512 * 128 * 2);
    ushort_t* WT1  = (ushort_t*)alloc((size_t)256 * 256 * 2);
    ushort_t* WT2  = (ushort_t*)alloc((size_t)128 * 256 * 2);
    ushort_t* Xb   = (ushort_t*)alloc((size_t)N_NODES * DIM * 2);
    ushort_t* Yb   = (ushort_t*)alloc((size_t)N_NODES * DIM * 2);
    ushort_t* Agg  = (ushort_t*)alloc((size_t)N_NODES * 384 * 2);
    ushort_t* Hidden = (ushort_t*)alloc((size_t)N_NODES * HMLP * 2);
    ushort_t* Cat  = Agg;

    const long ND = (long)N_NODES * DIM;
    dim3 blk256(256);
    dim3 grid_n((unsigned)((N_NODES + 255) / 256));
    dim3 grid_edges((unsigned)((N_EDGES + 255) / 256));
    const int MB128 = (N_NODES + 127) / 128;

    // ---- prep ----
    hipMemsetAsync(dega, 0, (size_t)N_NODES * 4, stream);
    hipMemsetAsync(stats, 0, (size_t)NLAYER * 2 * DIM * 4, stream);
    count_kernel<<<grid_edges, blk256, 0, stream>>>(edge_index, dega);
    bsum_kernel<<<dim3(NBLK_SCAN), blk256, 0, stream>>>(dega, bsum);
    bscan_kernel<<<dim3(1), blk256, 0, stream>>>(bsum, boff, rowptr);
    rowptr_kernel<<<dim3(NBLK_SCAN), blk256, 0, stream>>>(dega, boff, rowptr, cursor);
    fillpk_kernel<<<grid_edges, blk256, 0, stream>>>(edge_index, edge_attr, cursor, csr_pk);
    dinvseg_kernel<<<grid_n, blk256, 0, stream>>>(rowptr, csr_pk, dinv4);
    normfill_kernel<<<grid_n, blk256, 0, stream>>>(rowptr, csr_pk, dinv4, nrm);
    grp_kernel<<<grid_n, blk256, 0, stream>>>(batch, grp);
    wprep_kernel<<<dim3((NLAYER * 512 * 128 + 256 * 256 + 128 * 256 + NLAYER * 512 + 255) / 256),
                   blk256, 0, stream>>>(
        W_s, W_d, W_t, W_i, W_fc1, W_fc2, b_s, b_d, b_t, b_i, WTl, WT1, WT2, biascat);
    xcvt_kernel<<<dim3((unsigned)((ND / 4 + 255) / 256)), blk256, 0, stream>>>(x_in, (uint_t*)Xb);

    for (int l = 0; l < NLAYER; ++l) {
        gatherx_kernel<<<dim3((N_NODES + 7) / 8), blk256, 0, stream>>>(Xb, rowptr, nrm, Agg);
        flgemm_kernel<<<dim3(MB128), blk256, 0, stream>>>(
            Xb, Agg, WTl + (size_t)l * 512 * 128, biascat + (size_t)l * 512, Yb,
            stats + (size_t)l * 2 * DIM, N_NODES);
        bn_apply_kernel<<<dim3((unsigned)((ND / 2 + 255) / 256)), blk256, 0, stream>>>(
            Yb, stats + (size_t)l * 2 * DIM, gamma + (size_t)l * DIM, beta + (size_t)l * DIM, Xb);
    }

    // ---- pool + concat + MLP ----
    pool_kernel<<<dim3(NGRAPH), dim3(DIM), 0, stream>>>(Xb, grp, pooled);
    concat_kernel<<<dim3((unsigned)((N_NODES * 32 + 255) / 256)), blk256, 0, stream>>>(
        Xb, pooled, batch, Cat);
    mgemm_kernel<<<dim3((N_NODES + 127) / 128, 2), blk256, 0, stream>>>(
        Cat, WT1, b_fc1, nullptr, Hidden, N_NODES, 2 * DIM, MODE_BF16R, 0, HMLP);
    mgemm_kernel<<<dim3((N_NODES + 127) / 128, 1), blk256, 0, stream>>>(
        Hidden, WT2, b_fc2, out, nullptr, N_NODES, HMLP, MODE_F32, NCLS, NCLS);
}

// Round 12
// 426.793 us; speedup vs baseline: 1.0899x; 1.0075x over previous
//
#include <hip/hip_runtime.h>
#include <hip/hip_bf16.h>

#define N_NODES 50000
#define N_EDGES 600000
#define DIM     128
#define HMLP    256
#define NCLS    32
#define NGRAPH  512
#define NLAYER  3
#define BN_EPS  1e-5f
#define NBLK_SCAN ((N_NODES + 255) / 256)

typedef unsigned short ushort_t;
typedef unsigned int uint_t;
typedef __attribute__((ext_vector_type(8))) short short8v;
typedef __attribute__((ext_vector_type(4))) float f32x4;

#define MODE_BF16R 1
#define MODE_F32   2

__device__ __forceinline__ ushort_t f2b(float v) {
    __hip_bfloat16 h = __float2bfloat16(v);
    return *reinterpret_cast<ushort_t*>(&h);
}
__device__ __forceinline__ float b2f(ushort_t u) {
    __hip_bfloat16 h = *reinterpret_cast<__hip_bfloat16*>(&u);
    return __bfloat162float(h);
}
__device__ __forceinline__ float blo(uint_t h) { return b2f((ushort_t)(h & 0xffffu)); }
__device__ __forceinline__ float bhi(uint_t h) { return b2f((ushort_t)(h >> 16)); }

// ============ fused layer GEMM + BN-stats, T3 2-phase double-buffered ============
__global__ __launch_bounds__(256) void flgemm_kernel(
    const ushort_t* __restrict__ Xp,   // [N][128]
    const ushort_t* __restrict__ Agg,  // [N][384]
    const ushort_t* __restrict__ WT,   // [512][128]
    const float* __restrict__ biascat, // [512]
    ushort_t* __restrict__ Y,
    float* __restrict__ stats,         // [256]: sum | sumsq
    int M)
{
    __shared__ char lds[2 * 32768];    // per buf: As 128x64 (16KB) + Bs 128x64 (16KB)
    __shared__ float sh_s[128];
    __shared__ float sh_q[128];
    const int tid = threadIdx.x, lane = tid & 63, wv = tid >> 6;
    const int row0 = blockIdx.x * 128;
    const int fq = lane >> 4, fr = lane & 15;

    if (tid < 128) { sh_s[tid] = 0.f; sh_q[tid] = 0.f; }

    auto stage = [&](int t, int buf) {
        int p = t >> 1, k0 = (t & 1) * 64;
        const ushort_t* Ap = (p == 0) ? (Xp + (size_t)row0 * 128)
                                      : (Agg + (size_t)row0 * 384 + (p - 1) * 128);
        const int lda = (p == 0) ? 128 : 384;
        const ushort_t* Bp = WT + (size_t)p * 128 * 128;
        char* Asb = lds + buf * 32768;
        char* Bsb = Asb + 16384;
#pragma unroll
        for (int i = 0; i < 4; ++i) {
            int sid = i * 256 + tid;
            int r = sid >> 3, sl = sid & 7, sw = sl ^ (r & 7);
            int rr = (row0 + r < M) ? r : (M - 1 - row0);
            __builtin_amdgcn_global_load_lds(
                (const __attribute__((address_space(1))) unsigned int*)(Ap + (size_t)rr * lda + k0 + (sw << 3)),
                (__attribute__((address_space(3))) unsigned int*)(Asb + sid * 16), 16, 0, 0);
        }
#pragma unroll
        for (int i = 0; i < 4; ++i) {
            int sid = i * 256 + tid;
            int r = sid >> 3, sl = sid & 7, sw = sl ^ (r & 7);
            __builtin_amdgcn_global_load_lds(
                (const __attribute__((address_space(1))) unsigned int*)(Bp + (size_t)r * 128 + k0 + (sw << 3)),
                (__attribute__((address_space(3))) unsigned int*)(Bsb + sid * 16), 16, 0, 0);
        }
    };

    f32x4 tot[2][8] = {};
    f32x4 acc[2][8] = {};

    stage(0, 0);
    asm volatile("s_waitcnt vmcnt(0)" ::: "memory");
    __builtin_amdgcn_s_barrier();

    int cur = 0;
#pragma unroll
    for (int t = 0; t < 8; ++t) {
        if (t < 7) stage(t + 1, cur ^ 1);
        const char* Asb = lds + cur * 32768;
        const char* Bsb = Asb + 16384;
#pragma unroll
        for (int kk = 0; kk < 2; ++kk) {
            short8v a[2], b[8];
#pragma unroll
            for (int mf = 0; mf < 2; ++mf) {
                int ra = wv * 32 + mf * 16 + fr;
                a[mf] = *(const short8v*)(Asb + ra * 128 + (((kk * 4 + fq) ^ (ra & 7)) << 4));
            }
#pragma unroll
            for (int nf = 0; nf < 8; ++nf) {
                int rb = nf * 16 + fr;
                b[nf] = *(const short8v*)(Bsb + rb * 128 + (((kk * 4 + fq) ^ (rb & 7)) << 4));
            }
#pragma unroll
            for (int mf = 0; mf < 2; ++mf)
#pragma unroll
                for (int nf = 0; nf < 8; ++nf)
                    acc[mf][nf] = __builtin_amdgcn_mfma_f32_16x16x32_bf16(
                        a[mf], b[nf], acc[mf][nf], 0, 0, 0);
        }
        if (t & 1) {
            int p = t >> 1;
#pragma unroll
            for (int nf = 0; nf < 8; ++nf) {
                float bv = biascat[p * 128 + nf * 16 + fr];
#pragma unroll
                for (int mf = 0; mf < 2; ++mf) {
#pragma unroll
                    for (int j = 0; j < 4; ++j)
                        tot[mf][nf][j] += fmaxf(acc[mf][nf][j] + bv, 0.f);
                    acc[mf][nf] = f32x4{0.f, 0.f, 0.f, 0.f};
                }
            }
        }
        asm volatile("s_waitcnt vmcnt(0)" ::: "memory");
        __builtin_amdgcn_s_barrier();
        cur ^= 1;
    }

#pragma unroll
    for (int nf = 0; nf < 8; ++nf) {
        int col = nf * 16 + fr;
        float ps = 0.f, pq = 0.f;
#pragma unroll
        for (int mf = 0; mf < 2; ++mf) {
            int rowb = row0 + wv * 32 + mf * 16 + fq * 4;
#pragma unroll
            for (int j = 0; j < 4; ++j) {
                int r = rowb + j;
                if (r < M) {
                    float v = tot[mf][nf][j];
                    Y[(size_t)r * DIM + col] = f2b(v);
                    ps += v; pq += v * v;
                }
            }
        }
        atomicAdd(&sh_s[col], ps);
        atomicAdd(&sh_q[col], pq);
    }
    __syncthreads();
    if (tid < 128) {
        atomicAdd(&stats[tid], sh_s[tid]);
        atomicAdd(&stats[DIM + tid], sh_q[tid]);
    }
}

// ============ bf16 MFMA GEMM for fc1/fc2, T3 2-phase double-buffered ============
__global__ __launch_bounds__(256) void mgemm_kernel(
    const ushort_t* __restrict__ A, const ushort_t* __restrict__ BT,
    const float* __restrict__ bias,
    float* __restrict__ Cf, ushort_t* __restrict__ Cb,
    int M, int K, int mode, int ncmask, int ldc)
{
    __shared__ char lds[2 * 32768];
    const int tid = threadIdx.x, lane = tid & 63, wid = tid >> 6;
    const int wm = wid >> 1, wn = wid & 1;
    const int row0 = blockIdx.x * 128, col0 = blockIdx.y * 128;
    const int fq = lane >> 4, fr = lane & 15;

    f32x4 acc[4][4] = {};

    auto stage = [&](int k0, int buf) {
        char* Asb = lds + buf * 32768;
        char* Bsb = Asb + 16384;
#pragma unroll
        for (int i = 0; i < 4; ++i) {
            int sid = i * 256 + tid;
            int r = sid >> 3, sl = sid & 7, sw = sl ^ (r & 7);
            int gra = row0 + r; if (gra >= M) gra = M - 1;
            __builtin_amdgcn_global_load_lds(
                (const __attribute__((address_space(1))) unsigned int*)(A + (size_t)gra * K + k0 + (sw << 3)),
                (__attribute__((address_space(3))) unsigned int*)(Asb + sid * 16), 16, 0, 0);
        }
#pragma unroll
        for (int i = 0; i < 4; ++i) {
            int sid = i * 256 + tid;
            int r = sid >> 3, sl = sid & 7, sw = sl ^ (r & 7);
            __builtin_amdgcn_global_load_lds(
                (const __attribute__((address_space(1))) unsigned int*)(BT + (size_t)(col0 + r) * K + k0 + (sw << 3)),
                (__attribute__((address_space(3))) unsigned int*)(Bsb + sid * 16), 16, 0, 0);
        }
    };

    const int nk = K >> 6;
    stage(0, 0);
    asm volatile("s_waitcnt vmcnt(0)" ::: "memory");
    __builtin_amdgcn_s_barrier();

    int cur = 0;
    for (int kc = 0; kc < nk; ++kc) {
        if (kc + 1 < nk) stage((kc + 1) << 6, cur ^ 1);
        const char* Asb = lds + cur * 32768;
        const char* Bsb = Asb + 16384;
#pragma unroll
        for (int kk = 0; kk < 2; ++kk) {
            short8v a[4], b[4];
#pragma unroll
            for (int mf = 0; mf < 4; ++mf) {
                int ra = wm * 64 + mf * 16 + fr;
                a[mf] = *(const short8v*)(Asb + ra * 128 + (((kk * 4 + fq) ^ (ra & 7)) << 4));
                int rb = wn * 64 + mf * 16 + fr;
                b[mf] = *(const short8v*)(Bsb + rb * 128 + (((kk * 4 + fq) ^ (rb & 7)) << 4));
            }
#pragma unroll
            for (int mf = 0; mf < 4; ++mf)
#pragma unroll
                for (int nf = 0; nf < 4; ++nf)
                    acc[mf][nf] = __builtin_amdgcn_mfma_f32_16x16x32_bf16(
                        a[mf], b[nf], acc[mf][nf], 0, 0, 0);
        }
        asm volatile("s_waitcnt vmcnt(0)" ::: "memory");
        __builtin_amdgcn_s_barrier();
        cur ^= 1;
    }
#pragma unroll
    for (int mf = 0; mf < 4; ++mf) {
        int rowb = row0 + wm * 64 + mf * 16 + fq * 4;
#pragma unroll
        for (int nf = 0; nf < 4; ++nf) {
            int col = col0 + wn * 64 + nf * 16 + fr;
            f32x4 v = acc[mf][nf];
#pragma unroll
            for (int j = 0; j < 4; ++j) {
                int r = rowb + j;
                if (r >= M) continue;
                float val = v[j];
                if (mode == MODE_BF16R) {
                    Cb[(size_t)r * ldc + col] = f2b(fmaxf(val + bias[col], 0.f));
                } else {
                    if (col < ncmask) Cf[(size_t)r * ldc + col] = val + bias[col];
                }
            }
        }
    }
}

// ============ weight prep ============
__global__ void wprep_kernel(const float* __restrict__ W_s, const float* __restrict__ W_d,
                             const float* __restrict__ W_t, const float* __restrict__ W_i,
                             const float* __restrict__ W_fc1, const float* __restrict__ W_fc2,
                             const float* __restrict__ b_s, const float* __restrict__ b_d,
                             const float* __restrict__ b_t, const float* __restrict__ b_i,
                             ushort_t* __restrict__ WTl, ushort_t* __restrict__ WT1,
                             ushort_t* __restrict__ WT2, float* __restrict__ biascat)
{
    const int SZ_L = NLAYER * 512 * 128, SZ_1 = 256 * 256, SZ_2 = 128 * 256, SZ_B = NLAYER * 512;
    int idx = blockIdx.x * 256 + threadIdx.x;
    if (idx < SZ_L) {
        int l = idx / (512 * 128);
        int rem = idx - l * 512 * 128;
        int n = rem >> 7, k = rem & 127;
        float v;
        if (n < 128) v = W_i[((size_t)l * 128 + k) * 128 + n];
        else {
            int rel = (n - 128) >> 7, nn = (n - 128) & 127;
            const float* W = rel == 0 ? W_s : rel == 1 ? W_d : W_t;
            v = W[((size_t)l * 128 + k) * 128 + nn];
        }
        WTl[idx] = f2b(v);
    } else if (idx < SZ_L + SZ_1) {
        int j = idx - SZ_L;
        int n = j >> 8, k = j & 255;
        WT1[j] = f2b(W_fc1[(size_t)k * 256 + n]);
    } else if (idx < SZ_L + SZ_1 + SZ_2) {
        int j = idx - SZ_L - SZ_1;
        int n = j >> 8, k = j & 255;
        WT2[j] = f2b(n < 32 ? W_fc2[(size_t)k * 32 + n] : 0.f);
    } else if (idx < SZ_L + SZ_1 + SZ_2 + SZ_B) {
        int j = idx - SZ_L - SZ_1 - SZ_2;
        int l = j >> 9, rem = j & 511;
        int p = rem >> 7, c = rem & 127;
        const float* b = p == 0 ? b_i : p == 1 ? b_s : p == 2 ? b_d : b_t;
        biascat[j] = b[l * 128 + c];
    }
}

__global__ void xcvt_kernel(const float* __restrict__ x, uint_t* __restrict__ xb)
{
    long t = (long)blockIdx.x * 256 + threadIdx.x;
    if (t >= (long)N_NODES * DIM / 4) return;
    float4 v = *(const float4*)(x + t * 4);
    uint_t lo = (uint_t)f2b(v.x) | ((uint_t)f2b(v.y) << 16);
    uint_t hi = (uint_t)f2b(v.z) | ((uint_t)f2b(v.w) << 16);
    *(uint2*)(xb + t * 2) = make_uint2(lo, hi);
}

// ============ CSR build ============
__global__ void count_kernel(const int* __restrict__ ei, int* __restrict__ dega)
{
    int e = blockIdx.x * blockDim.x + threadIdx.x;
    if (e >= N_EDGES) return;
    atomicAdd(&dega[ei[N_EDGES + e]], 1);
}

__global__ void bsum_kernel(const int* __restrict__ dega, int* __restrict__ bsum)
{
    __shared__ int sh[256];
    int i = blockIdx.x * 256 + threadIdx.x;
    sh[threadIdx.x] = (i < N_NODES) ? dega[i] : 0;
    __syncthreads();
    for (int off = 128; off > 0; off >>= 1) {
        if (threadIdx.x < off) sh[threadIdx.x] += sh[threadIdx.x + off];
        __syncthreads();
    }
    if (threadIdx.x == 0) bsum[blockIdx.x] = sh[0];
}

__global__ void bscan_kernel(const int* __restrict__ bsum, int* __restrict__ boff,
                             int* __restrict__ rowptr)
{
    __shared__ int sh[256];
    int t = threadIdx.x;
    int v = (t < NBLK_SCAN) ? bsum[t] : 0;
    sh[t] = v;
    __syncthreads();
    for (int off = 1; off < 256; off <<= 1) {
        int u = (t >= off) ? sh[t - off] : 0;
        __syncthreads();
        sh[t] += u;
        __syncthreads();
    }
    if (t < NBLK_SCAN) boff[t] = sh[t] - v;
    if (t == 255) rowptr[N_NODES] = sh[255];
}

__global__ void rowptr_kernel(const int* __restrict__ dega, const int* __restrict__ boff,
                              int* __restrict__ rowptr, int* __restrict__ cursor)
{
    __shared__ int sh[256];
    int i = blockIdx.x * 256 + threadIdx.x;
    int t = threadIdx.x;
    int v = (i < N_NODES) ? dega[i] : 0;
    sh[t] = v;
    __syncthreads();
    for (int off = 1; off < 256; off <<= 1) {
        int u = (t >= off) ? sh[t - off] : 0;
        __syncthreads();
        sh[t] += u;
        __syncthreads();
    }
    if (i < N_NODES) {
        int e = boff[blockIdx.x] + sh[t] - v;
        rowptr[i] = e;
        cursor[i] = e;
    }
}

__global__ void fillpk_kernel(const int* __restrict__ ei, const int* __restrict__ ea,
                              int* __restrict__ cursor, uint_t* __restrict__ csr_pk)
{
    int e = blockIdx.x * blockDim.x + threadIdx.x;
    if (e >= N_EDGES) return;
    int r = ei[e], c = ei[N_EDGES + e];
    uint_t bits = (uint_t)(ea[e * 3 + 0] == 1) | ((uint_t)(ea[e * 3 + 1] == 1) << 1)
                | ((uint_t)(ea[e * 3 + 2] == 1) << 2);
    int slot = atomicAdd(&cursor[c], 1);
    csr_pk[slot] = (uint_t)r | (bits << 16);
}

__global__ void dinvseg_kernel(const int* __restrict__ rowptr, const uint_t* __restrict__ csr_pk,
                               float4* __restrict__ dinv4)
{
    int n = blockIdx.x * blockDim.x + threadIdx.x;
    if (n >= N_NODES) return;
    int p0 = rowptr[n], p1 = rowptr[n + 1];
    int d0 = 0, d1 = 0, d2 = 0;
    for (int p = p0; p < p1; ++p) {
        uint_t b = csr_pk[p] >> 16;
        d0 += b & 1; d1 += (b >> 1) & 1; d2 += (b >> 2) & 1;
    }
    float4 o;
    o.x = d0 ? rsqrtf((float)d0) : 0.f;
    o.y = d1 ? rsqrtf((float)d1) : 0.f;
    o.z = d2 ? rsqrtf((float)d2) : 0.f;
    o.w = 0.f;
    dinv4[n] = o;
}

__global__ void normfill_kernel(const int* __restrict__ rowptr, const uint_t* __restrict__ csr_pk,
                                const float4* __restrict__ dinv4, float4* __restrict__ nrm)
{
    int n = blockIdx.x * blockDim.x + threadIdx.x;
    if (n >= N_NODES) return;
    int p0 = rowptr[n], p1 = rowptr[n + 1];
    float4 dc = dinv4[n];
    for (int p = p0; p < p1; ++p) {
        uint_t pk = csr_pk[p];
        uint_t src = pk & 0xffffu, b = pk >> 16;
        float4 ds = dinv4[src];
        float4 m;
        m.x = (b & 1) ? ds.x * dc.x : 0.f;
        m.y = (b & 2) ? ds.y * dc.y : 0.f;
        m.z = (b & 4) ? ds.z * dc.z : 0.f;
        m.w = __uint_as_float(src);
        nrm[p] = m;
    }
}

// ============ gatherx: 4 nodes per wave (16 lanes, 8 ch/lane uint4), 4-edge unroll ============
__global__ __launch_bounds__(256) void gatherx_kernel(
    const ushort_t* __restrict__ Xb, const int* __restrict__ rowptr,
    const float4* __restrict__ nrm, ushort_t* __restrict__ Agg)
{
    int wv = threadIdx.x >> 6, lane = threadIdx.x & 63;
    int q = lane >> 4, ql = lane & 15;
    int n = blockIdx.x * 16 + wv * 4 + q;
    if (n >= N_NODES) return;
    int p0 = rowptr[n], p1 = rowptr[n + 1];
    const char* xbase = (const char*)Xb + (ql << 4);   // 8 channels/lane (16B)
    float c0[8] = {}, c1[8] = {}, c2[8] = {};

    for (int p = p0; p < p1; p += 4) {
        float4 m[4];
        uint4 xv[4];
#pragma unroll
        for (int u = 0; u < 4; ++u)
            m[u] = (p + u < p1) ? nrm[p + u] : make_float4(0.f, 0.f, 0.f, 0.f);
#pragma unroll
        for (int u = 0; u < 4; ++u)
            xv[u] = *(const uint4*)(xbase + ((size_t)__float_as_uint(m[u].w) << 8));
#pragma unroll
        for (int u = 0; u < 4; ++u) {
            float x[8] = { blo(xv[u].x), bhi(xv[u].x), blo(xv[u].y), bhi(xv[u].y),
                           blo(xv[u].z), bhi(xv[u].z), blo(xv[u].w), bhi(xv[u].w) };
#pragma unroll
            for (int j = 0; j < 8; ++j) {
                c0[j] = fmaf(m[u].x, x[j], c0[j]);
                c1[j] = fmaf(m[u].y, x[j], c1[j]);
                c2[j] = fmaf(m[u].z, x[j], c2[j]);
            }
        }
    }
    char* ab = (char*)Agg + (size_t)n * 768 + (ql << 4);
    uint4 o0 = { (uint_t)f2b(c0[0]) | ((uint_t)f2b(c0[1]) << 16),
                 (uint_t)f2b(c0[2]) | ((uint_t)f2b(c0[3]) << 16),
                 (uint_t)f2b(c0[4]) | ((uint_t)f2b(c0[5]) << 16),
                 (uint_t)f2b(c0[6]) | ((uint_t)f2b(c0[7]) << 16) };
    uint4 o1 = { (uint_t)f2b(c1[0]) | ((uint_t)f2b(c1[1]) << 16),
                 (uint_t)f2b(c1[2]) | ((uint_t)f2b(c1[3]) << 16),
                 (uint_t)f2b(c1[4]) | ((uint_t)f2b(c1[5]) << 16),
                 (uint_t)f2b(c1[6]) | ((uint_t)f2b(c1[7]) << 16) };
    uint4 o2 = { (uint_t)f2b(c2[0]) | ((uint_t)f2b(c2[1]) << 16),
                 (uint_t)f2b(c2[2]) | ((uint_t)f2b(c2[3]) << 16),
                 (uint_t)f2b(c2[4]) | ((uint_t)f2b(c2[5]) << 16),
                 (uint_t)f2b(c2[6]) | ((uint_t)f2b(c2[7]) << 16) };
    *(uint4*)(ab)       = o0;
    *(uint4*)(ab + 256) = o1;
    *(uint4*)(ab + 512) = o2;
}

// ============ BN apply ============
__global__ void bn_apply_kernel(const ushort_t* __restrict__ Y, const float* __restrict__ stats,
                                const float* __restrict__ gamma, const float* __restrict__ beta,
                                ushort_t* __restrict__ Xb)
{
    long t = (long)blockIdx.x * 256 + threadIdx.x;      // one uint = 2 channels
    if (t >= (long)N_NODES * DIM / 2) return;
    int ch = (int)(t & 63) * 2;
    const float invN = 1.f / (float)N_NODES;
    uint_t yv = ((const uint_t*)Y)[t];
    uint_t o = 0;
#pragma unroll
    for (int k = 0; k < 2; ++k) {
        int c = ch + k;
        float mu = stats[c] * invN;
        float var = stats[DIM + c] * invN - mu * mu;
        float inv = rsqrtf(var + BN_EPS);
        float y = (k == 0 ? blo(yv) : bhi(yv));
        float v = fmaxf((y - mu) * inv * gamma[c] + beta[c], 0.f);
        o |= ((uint_t)f2b(v)) << (k * 16);
    }
    ((uint_t*)Xb)[t] = o;
}

// ============ group boundaries + pool + concat ============
__global__ void grp_kernel(const int* __restrict__ batch, int* __restrict__ grp_start)
{
    int n = blockIdx.x * blockDim.x + threadIdx.x;
    if (n >= N_NODES) return;
    int b = batch[n];
    if (n == 0) { for (int g = 0; g <= b; ++g) grp_start[g] = 0; }
    else {
        int pb = batch[n - 1];
        for (int g = pb + 1; g <= b; ++g) grp_start[g] = n;
    }
    if (n == N_NODES - 1) { for (int g = b + 1; g <= NGRAPH; ++g) grp_start[g] = N_NODES; }
}

__global__ __launch_bounds__(128) void pool_kernel(const ushort_t* __restrict__ Xb,
                                                   const int* __restrict__ grp_start,
                                                   float* __restrict__ pooled)
{
    int g = blockIdx.x, ch = threadIdx.x;
    int r0 = grp_start[g], r1 = grp_start[g + 1];
    float s = 0.f;
    for (int r = r0; r < r1; ++r) s += b2f(Xb[(size_t)r * DIM + ch]);
    pooled[(size_t)g * DIM + ch] = s;
}

__global__ void concat_kernel(const ushort_t* __restrict__ Xb, const float* __restrict__ pooled,
                              const int* __restrict__ batch, ushort_t* __restrict__ Cat)
{
    long t = (long)blockIdx.x * blockDim.x + threadIdx.x;
    if (t >= (long)N_NODES * 32) return;
    int n = (int)(t >> 5), c8 = (int)(t & 31);
    if (c8 < 16) {
        *(uint4*)(Cat + (size_t)n * 256 + c8 * 8) =
            *(const uint4*)(Xb + (size_t)n * DIM + c8 * 8);
    } else {
        const float* ps = pooled + (size_t)batch[n] * DIM + (c8 - 16) * 8;
        float4 v0 = *(const float4*)ps, v1 = *(const float4*)(ps + 4);
        uint4 o;
        o.x = (uint_t)f2b(v0.x) | ((uint_t)f2b(v0.y) << 16);
        o.y = (uint_t)f2b(v0.z) | ((uint_t)f2b(v0.w) << 16);
        o.z = (uint_t)f2b(v1.x) | ((uint_t)f2b(v1.y) << 16);
        o.w = (uint_t)f2b(v1.z) | ((uint_t)f2b(v1.w) << 16);
        *(uint4*)(Cat + (size_t)n * 256 + c8 * 8) = o;
    }
}

extern "C" void kernel_launch(void* const* d_in, const int* in_sizes, int n_in,
                              void* d_out, int out_size, void* d_ws, size_t ws_size,
                              hipStream_t stream) {
    (void)in_sizes; (void)n_in; (void)out_size; (void)ws_size;
    const float* x_in = (const float*)d_in[0];
    const int* edge_index = (const int*)d_in[1];
    const int* edge_attr  = (const int*)d_in[2];
    const int* batch      = (const int*)d_in[3];
    const float* W_s   = (const float*)d_in[4];
    const float* b_s   = (const float*)d_in[5];
    const float* W_d   = (const float*)d_in[6];
    const float* b_d   = (const float*)d_in[7];
    const float* W_t   = (const float*)d_in[8];
    const float* b_t   = (const float*)d_in[9];
    const float* W_i   = (const float*)d_in[10];
    const float* b_i   = (const float*)d_in[11];
    const float* gamma = (const float*)d_in[12];
    const float* beta  = (const float*)d_in[13];
    const float* W_fc1 = (const float*)d_in[14];
    const float* b_fc1 = (const float*)d_in[15];
    const float* W_fc2 = (const float*)d_in[16];
    const float* b_fc2 = (const float*)d_in[17];
    float* out = (float*)d_out;

    // ---- workspace layout ----
    char* ws = (char*)d_ws;
    size_t off = 0;
    auto alloc = [&](size_t bytes) { char* p = ws + off; off += (bytes + 255) & ~(size_t)255; return p; };
    int*   dega    = (int*)  alloc((size_t)N_NODES * 4);
    int*   rowptr  = (int*)  alloc((size_t)(N_NODES + 1) * 4);
    int*   cursor  = (int*)  alloc((size_t)N_NODES * 4);
    int*   bsum    = (int*)  alloc(256 * 4);
    int*   boff    = (int*)  alloc(256 * 4);
    int*   grp     = (int*)  alloc((size_t)(NGRAPH + 1) * 4);
    uint_t* csr_pk = (uint_t*)alloc((size_t)N_EDGES * 4);
    float4* dinv4  = (float4*)alloc((size_t)N_NODES * 16);
    float4* nrm    = (float4*)alloc((size_t)(N_EDGES + 8) * 16);
    float* stats   = (float*)alloc((size_t)NLAYER * 2 * DIM * 4);
    float* pooled  = (float*)alloc((size_t)NGRAPH * DIM * 4);
    float* biascat = (float*)alloc((size_t)NLAYER * 512 * 4);
    ushort_t* WTl  = (ushort_t*)alloc((size_t)NLAYER * 512 * 128 * 2);
    ushort_t* WT1  = (ushort_t*)alloc((size_t)256 * 256 * 2);
    ushort_t* WT2  = (ushort_t*)alloc((size_t)128 * 256 * 2);
    ushort_t* Xb   = (ushort_t*)alloc((size_t)N_NODES * DIM * 2);
    ushort_t* Yb   = (ushort_t*)alloc((size_t)N_NODES * DIM * 2);
    ushort_t* Agg  = (ushort_t*)alloc((size_t)N_NODES * 384 * 2);
    ushort_t* Hidden = (ushort_t*)alloc((size_t)N_NODES * HMLP * 2);
    ushort_t* Cat  = Agg;

    const long ND = (long)N_NODES * DIM;
    dim3 blk256(256);
    dim3 grid_n((unsigned)((N_NODES + 255) / 256));
    dim3 grid_edges((unsigned)((N_EDGES + 255) / 256));
    const int MB128 = (N_NODES + 127) / 128;

    // ---- prep ----
    hipMemsetAsync(dega, 0, (size_t)N_NODES * 4, stream);
    hipMemsetAsync(stats, 0, (size_t)NLAYER * 2 * DIM * 4, stream);
    count_kernel<<<grid_edges, blk256, 0, stream>>>(edge_index, dega);
    bsum_kernel<<<dim3(NBLK_SCAN), blk256, 0, stream>>>(dega, bsum);
    bscan_kernel<<<dim3(1), blk256, 0, stream>>>(bsum, boff, rowptr);
    rowptr_kernel<<<dim3(NBLK_SCAN), blk256, 0, stream>>>(dega, boff, rowptr, cursor);
    fillpk_kernel<<<grid_edges, blk256, 0, stream>>>(edge_index, edge_attr, cursor, csr_pk);
    dinvseg_kernel<<<grid_n, blk256, 0, stream>>>(rowptr, csr_pk, dinv4);
    normfill_kernel<<<grid_n, blk256, 0, stream>>>(rowptr, csr_pk, dinv4, nrm);
    grp_kernel<<<grid_n, blk256, 0, stream>>>(batch, grp);
    wprep_kernel<<<dim3((NLAYER * 512 * 128 + 256 * 256 + 128 * 256 + NLAYER * 512 + 255) / 256),
                   blk256, 0, stream>>>(
        W_s, W_d, W_t, W_i, W_fc1, W_fc2, b_s, b_d, b_t, b_i, WTl, WT1, WT2, biascat);
    xcvt_kernel<<<dim3((unsigned)((ND / 4 + 255) / 256)), blk256, 0, stream>>>(x_in, (uint_t*)Xb);

    for (int l = 0; l < NLAYER; ++l) {
        gatherx_kernel<<<dim3((N_NODES + 15) / 16), blk256, 0, stream>>>(Xb, rowptr, nrm, Agg);
        flgemm_kernel<<<dim3(MB128), blk256, 0, stream>>>(
            Xb, Agg, WTl + (size_t)l * 512 * 128, biascat + (size_t)l * 512, Yb,
            stats + (size_t)l * 2 * DIM, N_NODES);
        bn_apply_kernel<<<dim3((unsigned)((ND / 2 + 255) / 256)), blk256, 0, stream>>>(
            Yb, stats + (size_t)l * 2 * DIM, gamma + (size_t)l * DIM, beta + (size_t)l * DIM, Xb);
    }

    // ---- pool + concat + MLP ----
    pool_kernel<<<dim3(NGRAPH), dim3(DIM), 0, stream>>>(Xb, grp, pooled);
    concat_kernel<<<dim3((unsigned)((N_NODES * 32 + 255) / 256)), blk256, 0, stream>>>(
        Xb, pooled, batch, Cat);
    mgemm_kernel<<<dim3(MB128, 2), blk256, 0, stream>>>(
        Cat, WT1, b_fc1, nullptr, Hidden, N_NODES, 2 * DIM, MODE_BF16R, 0, HMLP);
    mgemm_kernel<<<dim3(MB128, 1), blk256, 0, stream>>>(
        Hidden, WT2, b_fc2, out, nullptr, N_NODES, HMLP, MODE_F32, NCLS, NCLS);
}

// Round 13
// 395.845 us; speedup vs baseline: 1.1751x; 1.0782x over previous
//
#include <hip/hip_runtime.h>
#include <hip/hip_bf16.h>

#define N_NODES 50000
#define N_EDGES 600000
#define DIM     128
#define HMLP    256
#define NCLS    32
#define NGRAPH  512
#define NLAYER  3
#define BN_EPS  1e-5f
#define NBLK_SCAN ((N_NODES + 255) / 256)

typedef unsigned short ushort_t;
typedef unsigned int uint_t;
typedef __attribute__((ext_vector_type(8))) short short8v;
typedef __attribute__((ext_vector_type(4))) float f32x4;

__device__ __forceinline__ ushort_t f2b(float v) {
    __hip_bfloat16 h = __float2bfloat16(v);
    return *reinterpret_cast<ushort_t*>(&h);
}
__device__ __forceinline__ float b2f(ushort_t u) {
    __hip_bfloat16 h = *reinterpret_cast<__hip_bfloat16*>(&u);
    return __bfloat162float(h);
}
__device__ __forceinline__ float blo(uint_t h) { return b2f((ushort_t)(h & 0xffffu)); }
__device__ __forceinline__ float bhi(uint_t h) { return b2f((ushort_t)(h >> 16)); }

// ============ fused layer GEMM + BN-stats, T3 2-phase double-buffered ============
__global__ __launch_bounds__(256) void flgemm_kernel(
    const ushort_t* __restrict__ Xp,   // [N][128]
    const ushort_t* __restrict__ Agg,  // [N][384]
    const ushort_t* __restrict__ WT,   // [512][128]
    const float* __restrict__ biascat, // [512]
    ushort_t* __restrict__ Y,
    float* __restrict__ stats,         // [256]: sum | sumsq
    int M)
{
    __shared__ char lds[2 * 32768];    // per buf: As 128x64 (16KB) + Bs 128x64 (16KB)
    __shared__ float sh_s[128];
    __shared__ float sh_q[128];
    const int tid = threadIdx.x, lane = tid & 63, wv = tid >> 6;
    const int row0 = blockIdx.x * 128;
    const int fq = lane >> 4, fr = lane & 15;

    if (tid < 128) { sh_s[tid] = 0.f; sh_q[tid] = 0.f; }

    auto stage = [&](int t, int buf) {
        int p = t >> 1, k0 = (t & 1) * 64;
        const ushort_t* Ap = (p == 0) ? (Xp + (size_t)row0 * 128)
                                      : (Agg + (size_t)row0 * 384 + (p - 1) * 128);
        const int lda = (p == 0) ? 128 : 384;
        const ushort_t* Bp = WT + (size_t)p * 128 * 128;
        char* Asb = lds + buf * 32768;
        char* Bsb = Asb + 16384;
#pragma unroll
        for (int i = 0; i < 4; ++i) {
            int sid = i * 256 + tid;
            int r = sid >> 3, sl = sid & 7, sw = sl ^ (r & 7);
            int rr = (row0 + r < M) ? r : (M - 1 - row0);
            __builtin_amdgcn_global_load_lds(
                (const __attribute__((address_space(1))) unsigned int*)(Ap + (size_t)rr * lda + k0 + (sw << 3)),
                (__attribute__((address_space(3))) unsigned int*)(Asb + sid * 16), 16, 0, 0);
        }
#pragma unroll
        for (int i = 0; i < 4; ++i) {
            int sid = i * 256 + tid;
            int r = sid >> 3, sl = sid & 7, sw = sl ^ (r & 7);
            __builtin_amdgcn_global_load_lds(
                (const __attribute__((address_space(1))) unsigned int*)(Bp + (size_t)r * 128 + k0 + (sw << 3)),
                (__attribute__((address_space(3))) unsigned int*)(Bsb + sid * 16), 16, 0, 0);
        }
    };

    f32x4 tot[2][8] = {};
    f32x4 acc[2][8] = {};

    stage(0, 0);
    asm volatile("s_waitcnt vmcnt(0)" ::: "memory");
    __builtin_amdgcn_s_barrier();

    int cur = 0;
#pragma unroll
    for (int t = 0; t < 8; ++t) {
        if (t < 7) stage(t + 1, cur ^ 1);
        const char* Asb = lds + cur * 32768;
        const char* Bsb = Asb + 16384;
#pragma unroll
        for (int kk = 0; kk < 2; ++kk) {
            short8v a[2], b[8];
#pragma unroll
            for (int mf = 0; mf < 2; ++mf) {
                int ra = wv * 32 + mf * 16 + fr;
                a[mf] = *(const short8v*)(Asb + ra * 128 + (((kk * 4 + fq) ^ (ra & 7)) << 4));
            }
#pragma unroll
            for (int nf = 0; nf < 8; ++nf) {
                int rb = nf * 16 + fr;
                b[nf] = *(const short8v*)(Bsb + rb * 128 + (((kk * 4 + fq) ^ (rb & 7)) << 4));
            }
#pragma unroll
            for (int mf = 0; mf < 2; ++mf)
#pragma unroll
                for (int nf = 0; nf < 8; ++nf)
                    acc[mf][nf] = __builtin_amdgcn_mfma_f32_16x16x32_bf16(
                        a[mf], b[nf], acc[mf][nf], 0, 0, 0);
        }
        if (t & 1) {
            int p = t >> 1;
#pragma unroll
            for (int nf = 0; nf < 8; ++nf) {
                float bv = biascat[p * 128 + nf * 16 + fr];
#pragma unroll
                for (int mf = 0; mf < 2; ++mf) {
#pragma unroll
                    for (int j = 0; j < 4; ++j)
                        tot[mf][nf][j] += fmaxf(acc[mf][nf][j] + bv, 0.f);
                    acc[mf][nf] = f32x4{0.f, 0.f, 0.f, 0.f};
                }
            }
        }
        asm volatile("s_waitcnt vmcnt(0)" ::: "memory");
        __builtin_amdgcn_s_barrier();
        cur ^= 1;
    }

#pragma unroll
    for (int nf = 0; nf < 8; ++nf) {
        int col = nf * 16 + fr;
        float ps = 0.f, pq = 0.f;
#pragma unroll
        for (int mf = 0; mf < 2; ++mf) {
            int rowb = row0 + wv * 32 + mf * 16 + fq * 4;
#pragma unroll
            for (int j = 0; j < 4; ++j) {
                int r = rowb + j;
                if (r < M) {
                    float v = tot[mf][nf][j];
                    Y[(size_t)r * DIM + col] = f2b(v);
                    ps += v; pq += v * v;
                }
            }
        }
        atomicAdd(&sh_s[col], ps);
        atomicAdd(&sh_q[col], pq);
    }
    __syncthreads();
    if (tid < 128) {
        atomicAdd(&stats[tid], sh_s[tid]);
        atomicAdd(&stats[DIM + tid], sh_q[tid]);
    }
}

// ============ fc1: Hidden = relu([Xb | pooled_b[batch]] @ WT1^T + b), 2-phase ============
__global__ __launch_bounds__(256) void fc1gemm_kernel(
    const ushort_t* __restrict__ Xb,      // [N][128]
    const ushort_t* __restrict__ Pb,      // [G][128] bf16 pooled
    const int* __restrict__ batch,        // [N]
    const ushort_t* __restrict__ WT1,     // [256][256]
    const float* __restrict__ bias,
    ushort_t* __restrict__ Hidden, int M)
{
    __shared__ char lds[2 * 32768];
    const int tid = threadIdx.x, lane = tid & 63, wid = tid >> 6;
    const int wm = wid >> 1, wn = wid & 1;
    const int row0 = blockIdx.x * 128, col0 = blockIdx.y * 128;
    const int fq = lane >> 4, fr = lane & 15;

    f32x4 acc[4][4] = {};

    auto stage = [&](int k0, int buf) {
        char* Asb = lds + buf * 32768;
        char* Bsb = Asb + 16384;
#pragma unroll
        for (int i = 0; i < 4; ++i) {
            int sid = i * 256 + tid;
            int r = sid >> 3, sl = sid & 7, sw = sl ^ (r & 7);
            int gra = row0 + r; if (gra >= M) gra = M - 1;
            const ushort_t* srcA;
            if (k0 < 128) srcA = Xb + (size_t)gra * 128 + k0 + (sw << 3);
            else          srcA = Pb + (size_t)batch[gra] * 128 + (k0 - 128) + (sw << 3);
            __builtin_amdgcn_global_load_lds(
                (const __attribute__((address_space(1))) unsigned int*)srcA,
                (__attribute__((address_space(3))) unsigned int*)(Asb + sid * 16), 16, 0, 0);
        }
#pragma unroll
        for (int i = 0; i < 4; ++i) {
            int sid = i * 256 + tid;
            int r = sid >> 3, sl = sid & 7, sw = sl ^ (r & 7);
            __builtin_amdgcn_global_load_lds(
                (const __attribute__((address_space(1))) unsigned int*)(WT1 + (size_t)(col0 + r) * 256 + k0 + (sw << 3)),
                (__attribute__((address_space(3))) unsigned int*)(Bsb + sid * 16), 16, 0, 0);
        }
    };

    stage(0, 0);
    asm volatile("s_waitcnt vmcnt(0)" ::: "memory");
    __builtin_amdgcn_s_barrier();

    int cur = 0;
    for (int kc = 0; kc < 4; ++kc) {
        if (kc + 1 < 4) stage((kc + 1) << 6, cur ^ 1);
        const char* Asb = lds + cur * 32768;
        const char* Bsb = Asb + 16384;
#pragma unroll
        for (int kk = 0; kk < 2; ++kk) {
            short8v a[4], b[4];
#pragma unroll
            for (int mf = 0; mf < 4; ++mf) {
                int ra = wm * 64 + mf * 16 + fr;
                a[mf] = *(const short8v*)(Asb + ra * 128 + (((kk * 4 + fq) ^ (ra & 7)) << 4));
                int rb = wn * 64 + mf * 16 + fr;
                b[mf] = *(const short8v*)(Bsb + rb * 128 + (((kk * 4 + fq) ^ (rb & 7)) << 4));
            }
#pragma unroll
            for (int mf = 0; mf < 4; ++mf)
#pragma unroll
                for (int nf = 0; nf < 4; ++nf)
                    acc[mf][nf] = __builtin_amdgcn_mfma_f32_16x16x32_bf16(
                        a[mf], b[nf], acc[mf][nf], 0, 0, 0);
        }
        asm volatile("s_waitcnt vmcnt(0)" ::: "memory");
        __builtin_amdgcn_s_barrier();
        cur ^= 1;
    }
#pragma unroll
    for (int mf = 0; mf < 4; ++mf) {
        int rowb = row0 + wm * 64 + mf * 16 + fq * 4;
#pragma unroll
        for (int nf = 0; nf < 4; ++nf) {
            int col = col0 + wn * 64 + nf * 16 + fr;
            f32x4 v = acc[mf][nf];
#pragma unroll
            for (int j = 0; j < 4; ++j) {
                int r = rowb + j;
                if (r < M)
                    Hidden[(size_t)r * HMLP + col] = f2b(fmaxf(v[j] + bias[col], 0.f));
            }
        }
    }
}

// ============ fc2: out = Hidden @ WT2r^T + b (128x32 tile, no padding), 2-phase ============
__global__ __launch_bounds__(256) void fc2gemm_kernel(
    const ushort_t* __restrict__ A,     // [N][256]
    const ushort_t* __restrict__ BT,    // [32][256]
    const float* __restrict__ bias,
    float* __restrict__ out, int M)
{
    __shared__ char lds[2 * 20480];     // per buf: A 16KB + B 4KB
    const int tid = threadIdx.x, lane = tid & 63, wv = tid >> 6;
    const int row0 = blockIdx.x * 128;
    const int fq = lane >> 4, fr = lane & 15;

    f32x4 acc[2][2] = {};

    auto stage = [&](int k0, int buf) {
        char* Asb = lds + buf * 20480;
        char* Bsb = Asb + 16384;
#pragma unroll
        for (int i = 0; i < 4; ++i) {
            int sid = i * 256 + tid;
            int r = sid >> 3, sl = sid & 7, sw = sl ^ (r & 7);
            int gra = row0 + r; if (gra >= M) gra = M - 1;
            __builtin_amdgcn_global_load_lds(
                (const __attribute__((address_space(1))) unsigned int*)(A + (size_t)gra * 256 + k0 + (sw << 3)),
                (__attribute__((address_space(3))) unsigned int*)(Asb + sid * 16), 16, 0, 0);
        }
        if (tid < 256) {                 // B: 32 rows x 8 slots = 256 slots
            int sid = tid;
            int r = sid >> 3, sl = sid & 7, sw = sl ^ (r & 7);
            __builtin_amdgcn_global_load_lds(
                (const __attribute__((address_space(1))) unsigned int*)(BT + (size_t)r * 256 + k0 + (sw << 3)),
                (__attribute__((address_space(3))) unsigned int*)(Bsb + sid * 16), 16, 0, 0);
        }
    };

    stage(0, 0);
    asm volatile("s_waitcnt vmcnt(0)" ::: "memory");
    __builtin_amdgcn_s_barrier();

    int cur = 0;
    for (int kc = 0; kc < 4; ++kc) {
        if (kc + 1 < 4) stage((kc + 1) << 6, cur ^ 1);
        const char* Asb = lds + cur * 20480;
        const char* Bsb = Asb + 16384;
#pragma unroll
        for (int kk = 0; kk < 2; ++kk) {
            short8v a[2], b[2];
#pragma unroll
            for (int mf = 0; mf < 2; ++mf) {
                int ra = wv * 32 + mf * 16 + fr;
                a[mf] = *(const short8v*)(Asb + ra * 128 + (((kk * 4 + fq) ^ (ra & 7)) << 4));
            }
#pragma unroll
            for (int nf = 0; nf < 2; ++nf) {
                int rb = nf * 16 + fr;
                b[nf] = *(const short8v*)(Bsb + rb * 128 + (((kk * 4 + fq) ^ (rb & 7)) << 4));
            }
#pragma unroll
            for (int mf = 0; mf < 2; ++mf)
#pragma unroll
                for (int nf = 0; nf < 2; ++nf)
                    acc[mf][nf] = __builtin_amdgcn_mfma_f32_16x16x32_bf16(
                        a[mf], b[nf], acc[mf][nf], 0, 0, 0);
        }
        asm volatile("s_waitcnt vmcnt(0)" ::: "memory");
        __builtin_amdgcn_s_barrier();
        cur ^= 1;
    }
#pragma unroll
    for (int mf = 0; mf < 2; ++mf) {
        int rowb = row0 + wv * 32 + mf * 16 + fq * 4;
#pragma unroll
        for (int nf = 0; nf < 2; ++nf) {
            int col = nf * 16 + fr;
            f32x4 v = acc[mf][nf];
#pragma unroll
            for (int j = 0; j < 4; ++j) {
                int r = rowb + j;
                if (r < M) out[(size_t)r * NCLS + col] = v[j] + bias[col];
            }
        }
    }
}

// ============ weight prep ============
__global__ void wprep_kernel(const float* __restrict__ W_s, const float* __restrict__ W_d,
                             const float* __restrict__ W_t, const float* __restrict__ W_i,
                             const float* __restrict__ W_fc1, const float* __restrict__ W_fc2,
                             const float* __restrict__ b_s, const float* __restrict__ b_d,
                             const float* __restrict__ b_t, const float* __restrict__ b_i,
                             ushort_t* __restrict__ WTl, ushort_t* __restrict__ WT1,
                             ushort_t* __restrict__ WT2, float* __restrict__ biascat)
{
    const int SZ_L = NLAYER * 512 * 128, SZ_1 = 256 * 256, SZ_2 = 32 * 256, SZ_B = NLAYER * 512;
    int idx = blockIdx.x * 256 + threadIdx.x;
    if (idx < SZ_L) {
        int l = idx / (512 * 128);
        int rem = idx - l * 512 * 128;
        int n = rem >> 7, k = rem & 127;
        float v;
        if (n < 128) v = W_i[((size_t)l * 128 + k) * 128 + n];
        else {
            int rel = (n - 128) >> 7, nn = (n - 128) & 127;
            const float* W = rel == 0 ? W_s : rel == 1 ? W_d : W_t;
            v = W[((size_t)l * 128 + k) * 128 + nn];
        }
        WTl[idx] = f2b(v);
    } else if (idx < SZ_L + SZ_1) {
        int j = idx - SZ_L;
        int n = j >> 8, k = j & 255;
        WT1[j] = f2b(W_fc1[(size_t)k * 256 + n]);
    } else if (idx < SZ_L + SZ_1 + SZ_2) {
        int j = idx - SZ_L - SZ_1;
        int n = j >> 8, k = j & 255;
        WT2[j] = f2b(W_fc2[(size_t)k * 32 + n]);
    } else if (idx < SZ_L + SZ_1 + SZ_2 + SZ_B) {
        int j = idx - SZ_L - SZ_1 - SZ_2;
        int l = j >> 9, rem = j & 511;
        int p = rem >> 7, c = rem & 127;
        const float* b = p == 0 ? b_i : p == 1 ? b_s : p == 2 ? b_d : b_t;
        biascat[j] = b[l * 128 + c];
    }
}

__global__ void xcvt_kernel(const float* __restrict__ x, uint_t* __restrict__ xb)
{
    long t = (long)blockIdx.x * 256 + threadIdx.x;
    if (t >= (long)N_NODES * DIM / 4) return;
    float4 v = *(const float4*)(x + t * 4);
    uint_t lo = (uint_t)f2b(v.x) | ((uint_t)f2b(v.y) << 16);
    uint_t hi = (uint_t)f2b(v.z) | ((uint_t)f2b(v.w) << 16);
    *(uint2*)(xb + t * 2) = make_uint2(lo, hi);
}

// ============ CSR build ============
__global__ void count_kernel(const int* __restrict__ ei, int* __restrict__ dega)
{
    int e = blockIdx.x * blockDim.x + threadIdx.x;
    if (e >= N_EDGES) return;
    atomicAdd(&dega[ei[N_EDGES + e]], 1);
}

__global__ void bsum_kernel(const int* __restrict__ dega, int* __restrict__ bsum)
{
    __shared__ int sh[256];
    int i = blockIdx.x * 256 + threadIdx.x;
    sh[threadIdx.x] = (i < N_NODES) ? dega[i] : 0;
    __syncthreads();
    for (int off = 128; off > 0; off >>= 1) {
        if (threadIdx.x < off) sh[threadIdx.x] += sh[threadIdx.x + off];
        __syncthreads();
    }
    if (threadIdx.x == 0) bsum[blockIdx.x] = sh[0];
}

__global__ void bscan_kernel(const int* __restrict__ bsum, int* __restrict__ boff,
                             int* __restrict__ rowptr)
{
    __shared__ int sh[256];
    int t = threadIdx.x;
    int v = (t < NBLK_SCAN) ? bsum[t] : 0;
    sh[t] = v;
    __syncthreads();
    for (int off = 1; off < 256; off <<= 1) {
        int u = (t >= off) ? sh[t - off] : 0;
        __syncthreads();
        sh[t] += u;
        __syncthreads();
    }
    if (t < NBLK_SCAN) boff[t] = sh[t] - v;
    if (t == 255) rowptr[N_NODES] = sh[255];
}

__global__ void rowptr_kernel(const int* __restrict__ dega, const int* __restrict__ boff,
                              int* __restrict__ rowptr, int* __restrict__ cursor)
{
    __shared__ int sh[256];
    int i = blockIdx.x * 256 + threadIdx.x;
    int t = threadIdx.x;
    int v = (i < N_NODES) ? dega[i] : 0;
    sh[t] = v;
    __syncthreads();
    for (int off = 1; off < 256; off <<= 1) {
        int u = (t >= off) ? sh[t - off] : 0;
        __syncthreads();
        sh[t] += u;
        __syncthreads();
    }
    if (i < N_NODES) {
        int e = boff[blockIdx.x] + sh[t] - v;
        rowptr[i] = e;
        cursor[i] = e;
    }
}

__global__ void fillpk_kernel(const int* __restrict__ ei, const int* __restrict__ ea,
                              int* __restrict__ cursor, uint_t* __restrict__ csr_pk)
{
    int e = blockIdx.x * blockDim.x + threadIdx.x;
    if (e >= N_EDGES) return;
    int r = ei[e], c = ei[N_EDGES + e];
    uint_t bits = (uint_t)(ea[e * 3 + 0] == 1) | ((uint_t)(ea[e * 3 + 1] == 1) << 1)
                | ((uint_t)(ea[e * 3 + 2] == 1) << 2);
    int slot = atomicAdd(&cursor[c], 1);
    csr_pk[slot] = (uint_t)r | (bits << 16);
}

__global__ void dinvseg_kernel(const int* __restrict__ rowptr, const uint_t* __restrict__ csr_pk,
                               float4* __restrict__ dinv4)
{
    int n = blockIdx.x * blockDim.x + threadIdx.x;
    if (n >= N_NODES) return;
    int p0 = rowptr[n], p1 = rowptr[n + 1];
    int d0 = 0, d1 = 0, d2 = 0;
    for (int p = p0; p < p1; ++p) {
        uint_t b = csr_pk[p] >> 16;
        d0 += b & 1; d1 += (b >> 1) & 1; d2 += (b >> 2) & 1;
    }
    float4 o;
    o.x = d0 ? rsqrtf((float)d0) : 0.f;
    o.y = d1 ? rsqrtf((float)d1) : 0.f;
    o.z = d2 ? rsqrtf((float)d2) : 0.f;
    o.w = 0.f;
    dinv4[n] = o;
}

__global__ void normfill_kernel(const int* __restrict__ rowptr, const uint_t* __restrict__ csr_pk,
                                const float4* __restrict__ dinv4, float4* __restrict__ nrm)
{
    int n = blockIdx.x * blockDim.x + threadIdx.x;
    if (n >= N_NODES) return;
    int p0 = rowptr[n], p1 = rowptr[n + 1];
    float4 dc = dinv4[n];
    for (int p = p0; p < p1; ++p) {
        uint_t pk = csr_pk[p];
        uint_t src = pk & 0xffffu, b = pk >> 16;
        float4 ds = dinv4[src];
        float4 m;
        m.x = (b & 1) ? ds.x * dc.x : 0.f;
        m.y = (b & 2) ? ds.y * dc.y : 0.f;
        m.z = (b & 4) ? ds.z * dc.z : 0.f;
        m.w = __uint_as_float(src);
        nrm[p] = m;
    }
}

// ============ gatherx: 4 nodes per wave (16 lanes, 8 ch/lane uint4), 4-edge unroll ============
__global__ __launch_bounds__(256) void gatherx_kernel(
    const ushort_t* __restrict__ Xb, const int* __restrict__ rowptr,
    const float4* __restrict__ nrm, ushort_t* __restrict__ Agg)
{
    int wv = threadIdx.x >> 6, lane = threadIdx.x & 63;
    int q = lane >> 4, ql = lane & 15;
    int n = blockIdx.x * 16 + wv * 4 + q;
    if (n >= N_NODES) return;
    int p0 = rowptr[n], p1 = rowptr[n + 1];
    const char* xbase = (const char*)Xb + (ql << 4);   // 8 channels/lane (16B)
    float c0[8] = {}, c1[8] = {}, c2[8] = {};

    for (int p = p0; p < p1; p += 4) {
        float4 m[4];
        uint4 xv[4];
#pragma unroll
        for (int u = 0; u < 4; ++u)
            m[u] = (p + u < p1) ? nrm[p + u] : make_float4(0.f, 0.f, 0.f, 0.f);
#pragma unroll
        for (int u = 0; u < 4; ++u)
            xv[u] = *(const uint4*)(xbase + ((size_t)__float_as_uint(m[u].w) << 8));
#pragma unroll
        for (int u = 0; u < 4; ++u) {
            float x[8] = { blo(xv[u].x), bhi(xv[u].x), blo(xv[u].y), bhi(xv[u].y),
                           blo(xv[u].z), bhi(xv[u].z), blo(xv[u].w), bhi(xv[u].w) };
#pragma unroll
            for (int j = 0; j < 8; ++j) {
                c0[j] = fmaf(m[u].x, x[j], c0[j]);
                c1[j] = fmaf(m[u].y, x[j], c1[j]);
                c2[j] = fmaf(m[u].z, x[j], c2[j]);
            }
        }
    }
    char* ab = (char*)Agg + (size_t)n * 768 + (ql << 4);
    uint4 o0 = { (uint_t)f2b(c0[0]) | ((uint_t)f2b(c0[1]) << 16),
                 (uint_t)f2b(c0[2]) | ((uint_t)f2b(c0[3]) << 16),
                 (uint_t)f2b(c0[4]) | ((uint_t)f2b(c0[5]) << 16),
                 (uint_t)f2b(c0[6]) | ((uint_t)f2b(c0[7]) << 16) };
    uint4 o1 = { (uint_t)f2b(c1[0]) | ((uint_t)f2b(c1[1]) << 16),
                 (uint_t)f2b(c1[2]) | ((uint_t)f2b(c1[3]) << 16),
                 (uint_t)f2b(c1[4]) | ((uint_t)f2b(c1[5]) << 16),
                 (uint_t)f2b(c1[6]) | ((uint_t)f2b(c1[7]) << 16) };
    uint4 o2 = { (uint_t)f2b(c2[0]) | ((uint_t)f2b(c2[1]) << 16),
                 (uint_t)f2b(c2[2]) | ((uint_t)f2b(c2[3]) << 16),
                 (uint_t)f2b(c2[4]) | ((uint_t)f2b(c2[5]) << 16),
                 (uint_t)f2b(c2[6]) | ((uint_t)f2b(c2[7]) << 16) };
    *(uint4*)(ab)       = o0;
    *(uint4*)(ab + 256) = o1;
    *(uint4*)(ab + 512) = o2;
}

// ============ BN apply ============
__global__ void bn_apply_kernel(const ushort_t* __restrict__ Y, const float* __restrict__ stats,
                                const float* __restrict__ gamma, const float* __restrict__ beta,
                                ushort_t* __restrict__ Xb)
{
    long t = (long)blockIdx.x * 256 + threadIdx.x;      // one uint = 2 channels
    if (t >= (long)N_NODES * DIM / 2) return;
    int ch = (int)(t & 63) * 2;
    const float invN = 1.f / (float)N_NODES;
    uint_t yv = ((const uint_t*)Y)[t];
    uint_t o = 0;
#pragma unroll
    for (int k = 0; k < 2; ++k) {
        int c = ch + k;
        float mu = stats[c] * invN;
        float var = stats[DIM + c] * invN - mu * mu;
        float inv = rsqrtf(var + BN_EPS);
        float y = (k == 0 ? blo(yv) : bhi(yv));
        float v = fmaxf((y - mu) * inv * gamma[c] + beta[c], 0.f);
        o |= ((uint_t)f2b(v)) << (k * 16);
    }
    ((uint_t*)Xb)[t] = o;
}

// ============ group boundaries + pool (bf16 out) ============
__global__ void grp_kernel(const int* __restrict__ batch, int* __restrict__ grp_start)
{
    int n = blockIdx.x * blockDim.x + threadIdx.x;
    if (n >= N_NODES) return;
    int b = batch[n];
    if (n == 0) { for (int g = 0; g <= b; ++g) grp_start[g] = 0; }
    else {
        int pb = batch[n - 1];
        for (int g = pb + 1; g <= b; ++g) grp_start[g] = n;
    }
    if (n == N_NODES - 1) { for (int g = b + 1; g <= NGRAPH; ++g) grp_start[g] = N_NODES; }
}

__global__ __launch_bounds__(256) void pool_kernel(const ushort_t* __restrict__ Xb,
                                                   const int* __restrict__ grp_start,
                                                   ushort_t* __restrict__ pooled_b)
{
    __shared__ float sh[2][128];
    int g = blockIdx.x;
    int ch = threadIdx.x & 127, rl = threadIdx.x >> 7;
    int r0 = grp_start[g], r1 = grp_start[g + 1];
    float s = 0.f;
    for (int r = r0 + rl; r < r1; r += 2) s += b2f(Xb[(size_t)r * DIM + ch]);
    sh[rl][ch] = s;
    __syncthreads();
    if (threadIdx.x < 128)
        pooled_b[(size_t)g * DIM + threadIdx.x] = f2b(sh[0][threadIdx.x] + sh[1][threadIdx.x]);
}

extern "C" void kernel_launch(void* const* d_in, const int* in_sizes, int n_in,
                              void* d_out, int out_size, void* d_ws, size_t ws_size,
                              hipStream_t stream) {
    (void)in_sizes; (void)n_in; (void)out_size; (void)ws_size;
    const float* x_in = (const float*)d_in[0];
    const int* edge_index = (const int*)d_in[1];
    const int* edge_attr  = (const int*)d_in[2];
    const int* batch      = (const int*)d_in[3];
    const float* W_s   = (const float*)d_in[4];
    const float* b_s   = (const float*)d_in[5];
    const float* W_d   = (const float*)d_in[6];
    const float* b_d   = (const float*)d_in[7];
    const float* W_t   = (const float*)d_in[8];
    const float* b_t   = (const float*)d_in[9];
    const float* W_i   = (const float*)d_in[10];
    const float* b_i   = (const float*)d_in[11];
    const float* gamma = (const float*)d_in[12];
    const float* beta  = (const float*)d_in[13];
    const float* W_fc1 = (const float*)d_in[14];
    const float* b_fc1 = (const float*)d_in[15];
    const float* W_fc2 = (const float*)d_in[16];
    const float* b_fc2 = (const float*)d_in[17];
    float* out = (float*)d_out;

    // ---- workspace layout ----
    char* ws = (char*)d_ws;
    size_t off = 0;
    auto alloc = [&](size_t bytes) { char* p = ws + off; off += (bytes + 255) & ~(size_t)255; return p; };
    int*   dega    = (int*)  alloc((size_t)N_NODES * 4);
    int*   rowptr  = (int*)  alloc((size_t)(N_NODES + 1) * 4);
    int*   cursor  = (int*)  alloc((size_t)N_NODES * 4);
    int*   bsum    = (int*)  alloc(256 * 4);
    int*   boff    = (int*)  alloc(256 * 4);
    int*   grp     = (int*)  alloc((size_t)(NGRAPH + 1) * 4);
    uint_t* csr_pk = (uint_t*)alloc((size_t)N_EDGES * 4);
    float4* dinv4  = (float4*)alloc((size_t)N_NODES * 16);
    float4* nrm    = (float4*)alloc((size_t)(N_EDGES + 8) * 16);
    float* stats   = (float*)alloc((size_t)NLAYER * 2 * DIM * 4);
    float* biascat = (float*)alloc((size_t)NLAYER * 512 * 4);
    ushort_t* pooled_b = (ushort_t*)alloc((size_t)NGRAPH * DIM * 2);
    ushort_t* WTl  = (ushort_t*)alloc((size_t)NLAYER * 512 * 128 * 2);
    ushort_t* WT1  = (ushort_t*)alloc((size_t)256 * 256 * 2);
    ushort_t* WT2  = (ushort_t*)alloc((size_t)32 * 256 * 2);
    ushort_t* Xb   = (ushort_t*)alloc((size_t)N_NODES * DIM * 2);
    ushort_t* Yb   = (ushort_t*)alloc((size_t)N_NODES * DIM * 2);
    ushort_t* Agg  = (ushort_t*)alloc((size_t)N_NODES * 384 * 2);
    ushort_t* Hidden = (ushort_t*)alloc((size_t)N_NODES * HMLP * 2);

    const long ND = (long)N_NODES * DIM;
    dim3 blk256(256);
    dim3 grid_n((unsigned)((N_NODES + 255) / 256));
    dim3 grid_edges((unsigned)((N_EDGES + 255) / 256));
    const int MB128 = (N_NODES + 127) / 128;

    // ---- prep ----
    hipMemsetAsync(dega, 0, (size_t)N_NODES * 4, stream);
    hipMemsetAsync(stats, 0, (size_t)NLAYER * 2 * DIM * 4, stream);
    count_kernel<<<grid_edges, blk256, 0, stream>>>(edge_index, dega);
    bsum_kernel<<<dim3(NBLK_SCAN), blk256, 0, stream>>>(dega, bsum);
    bscan_kernel<<<dim3(1), blk256, 0, stream>>>(bsum, boff, rowptr);
    rowptr_kernel<<<dim3(NBLK_SCAN), blk256, 0, stream>>>(dega, boff, rowptr, cursor);
    fillpk_kernel<<<grid_edges, blk256, 0, stream>>>(edge_index, edge_attr, cursor, csr_pk);
    dinvseg_kernel<<<grid_n, blk256, 0, stream>>>(rowptr, csr_pk, dinv4);
    normfill_kernel<<<grid_n, blk256, 0, stream>>>(rowptr, csr_pk, dinv4, nrm);
    grp_kernel<<<grid_n, blk256, 0, stream>>>(batch, grp);
    wprep_kernel<<<dim3((NLAYER * 512 * 128 + 256 * 256 + 32 * 256 + NLAYER * 512 + 255) / 256),
                   blk256, 0, stream>>>(
        W_s, W_d, W_t, W_i, W_fc1, W_fc2, b_s, b_d, b_t, b_i, WTl, WT1, WT2, biascat);
    xcvt_kernel<<<dim3((unsigned)((ND / 4 + 255) / 256)), blk256, 0, stream>>>(x_in, (uint_t*)Xb);

    for (int l = 0; l < NLAYER; ++l) {
        gatherx_kernel<<<dim3((N_NODES + 15) / 16), blk256, 0, stream>>>(Xb, rowptr, nrm, Agg);
        flgemm_kernel<<<dim3(MB128), blk256, 0, stream>>>(
            Xb, Agg, WTl + (size_t)l * 512 * 128, biascat + (size_t)l * 512, Yb,
            stats + (size_t)l * 2 * DIM, N_NODES);
        bn_apply_kernel<<<dim3((unsigned)((ND / 2 + 255) / 256)), blk256, 0, stream>>>(
            Yb, stats + (size_t)l * 2 * DIM, gamma + (size_t)l * DIM, beta + (size_t)l * DIM, Xb);
    }

    // ---- pool + MLP (concat fused into fc1 staging) ----
    pool_kernel<<<dim3(NGRAPH), blk256, 0, stream>>>(Xb, grp, pooled_b);
    fc1gemm_kernel<<<dim3(MB128, 2), blk256, 0, stream>>>(
        Xb, pooled_b, batch, WT1, b_fc1, Hidden, N_NODES);
    fc2gemm_kernel<<<dim3(MB128), blk256, 0, stream>>>(
        Hidden, WT2, b_fc2, out, N_NODES);
}